// Round 6
// baseline (395.054 us; speedup 1.0000x reference)
//
#include <hip/hip_runtime.h>

typedef short bf16x8 __attribute__((ext_vector_type(8)));
typedef float f32x4 __attribute__((ext_vector_type(4)));

#define NB 2
#define NN 20000
#define ME 320000
#define STRIPES 64
#define NT_FB 8  // tiles per block, fallback edge kernel
#define NT2 5    // tiles per block, new edge kernel (5000 tiles / 1000 blocks)

__device__ __forceinline__ unsigned short f2bf(float f) {
  union { float f; unsigned int u; } v; v.f = f;
  unsigned int r = (v.u + 0x7FFFu + ((v.u >> 16) & 1u)) >> 16;  // RNE
  return (unsigned short)r;
}

__device__ __forceinline__ bf16x8 pack2(float4 a, float4 b) {
  bf16x8 v;
  v[0]=(short)f2bf(a.x); v[1]=(short)f2bf(a.y); v[2]=(short)f2bf(a.z); v[3]=(short)f2bf(a.w);
  v[4]=(short)f2bf(b.x); v[5]=(short)f2bf(b.y); v[6]=(short)f2bf(b.z); v[7]=(short)f2bf(b.w);
  return v;
}

__device__ __forceinline__ f32x4 mfma16(bf16x8 a, bf16x8 b, f32x4 c) {
  return __builtin_amdgcn_mfma_f32_16x16x32_bf16(a, b, c, 0, 0, 0);
}

// hidden-col interleave: table col c holds hidden column hid(c) = (c&~31) + 2*(c&15) + ((c>>4)&1),
// so a wave's frag pair (nt=0,nt=1) at lane fc covers adjacent hidden cols (2fc, 2fc+1).
__device__ __forceinline__ int hidcol(int c) {
  return (c & ~31) + 2 * (c & 15) + ((c >> 4) & 1);
}

// ================= new path =================

__global__ void prep_w2(const float* __restrict__ eW1, const float* __restrict__ eW2,
                        const float* __restrict__ nW1, const float* __restrict__ nW2,
                        const float* __restrict__ pW,
                        short* __restrict__ es1T, short* __restrict__ ed1T,
                        short* __restrict__ w1eT, short* __restrict__ ew2T,
                        short* __restrict__ nw1T, short* __restrict__ nw2T,
                        short* __restrict__ pwT) {
  int c = blockIdx.x;   // 0..127 table column
  int t = threadIdx.x;  // 256
  int hc = hidcol(c);
  if (t < 128) {
    es1T[c * 128 + t] = (short)f2bf(eW1[(size_t)t * 128 + hc]);
    ed1T[c * 128 + t] = (short)f2bf(eW1[(size_t)(128 + t) * 128 + hc]);
    ew2T[c * 128 + t] = (short)f2bf(eW2[(size_t)t * 128 + c]);
    nw1T[c * 128 + t] = (short)f2bf(nW1[(size_t)t * 128 + c]);
    nw2T[c * 128 + t] = (short)f2bf(nW2[(size_t)t * 128 + c]);
  }
  if (t < 32) {
    w1eT[c * 32 + t] = (t < 16) ? (short)f2bf(eW1[(size_t)(256 + t) * 128 + hc]) : (short)0;
    pwT[c * 32 + t]  = (t < 16) ? (short)f2bf(pW[(size_t)t * 128 + c]) : (short)0;
  }
}

// node_prep: per 64-node tile, stage X once; emit f32 Xs = X@eW1[0:128] (hidden-linear
// cols), f32 Xd = X@eW1[128:256], and the node-MLP Hx column-sums.
__global__ __launch_bounds__(256, 4) void node_prep(
    const float* __restrict__ X,
    const short* __restrict__ nw1T, const short* __restrict__ nw2T,
    const short* __restrict__ es1T, const short* __restrict__ ed1T,
    const float* __restrict__ nb1, const float* __restrict__ nb2,
    float* __restrict__ Xs, float* __restrict__ Xd,
    float* __restrict__ node_acc) {
  __shared__ __align__(16) short A_lds[64 * 136];
  __shared__ __align__(16) short B_lds[64 * 136];
  const int tid = threadIdx.x;
  const int lane = tid & 63;
  const int w = tid >> 6;
  const int fc = lane & 15;
  const int fg = lane >> 4;
  const int ncol0 = w * 32;
  const int b = blockIdx.y;
  const int n0 = blockIdx.x * 64;
  const float* X_b = X + (size_t)b * NN * 128;
  float* Xs_b = Xs + (size_t)b * NN * 128;
  float* Xd_b = Xd + (size_t)b * NN * 128;
  const f32x4 zf = {0.f, 0.f, 0.f, 0.f};

  // stage X tile (bf16, RNE)
#pragma unroll
  for (int p = 0; p < 8; ++p) {
    int slot = p * 256 + tid;
    int row = slot >> 5, chunk = slot & 31;
    int node = n0 + row;
    uint2 v = {0, 0};
    if (node < NN) {
      float4 f = *(const float4*)(X_b + (size_t)node * 128 + chunk * 4);
      v.x = (unsigned)f2bf(f.x) | ((unsigned)f2bf(f.y) << 16);
      v.y = (unsigned)f2bf(f.z) | ((unsigned)f2bf(f.w) << 16);
    }
    *(uint2*)(&A_lds[row * 136 + chunk * 4]) = v;
  }
  __syncthreads();

  // ---- GEMM-S -> direct f32 store (hidden-linear: cols ncol0+2fc, +1) ----
  {
    bf16x8 BS[2][4];
#pragma unroll
    for (int nt = 0; nt < 2; ++nt)
#pragma unroll
      for (int kt = 0; kt < 4; ++kt)
        BS[nt][kt] = *(const bf16x8*)(es1T + (ncol0 + nt * 16 + fc) * 128 + kt * 32 + fg * 8);
#pragma unroll
    for (int rt = 0; rt < 4; ++rt) {
      f32x4 a0 = zf, a1 = zf;
#pragma unroll
      for (int kt = 0; kt < 4; ++kt) {
        bf16x8 av = *(const bf16x8*)(&A_lds[(rt * 16 + fc) * 136 + kt * 32 + fg * 8]);
        a0 = mfma16(av, BS[0][kt], a0);
        a1 = mfma16(av, BS[1][kt], a1);
      }
#pragma unroll
      for (int r = 0; r < 4; ++r) {
        int node = n0 + rt * 16 + fg * 4 + r;
        if (node < NN) {
          float2 o; o.x = a0[r]; o.y = a1[r];
          *(float2*)(Xs_b + (size_t)node * 128 + ncol0 + 2 * fc) = o;
        }
      }
    }
  }
  // ---- GEMM-D -> direct f32 store ----
  {
    bf16x8 BD[2][4];
#pragma unroll
    for (int nt = 0; nt < 2; ++nt)
#pragma unroll
      for (int kt = 0; kt < 4; ++kt)
        BD[nt][kt] = *(const bf16x8*)(ed1T + (ncol0 + nt * 16 + fc) * 128 + kt * 32 + fg * 8);
#pragma unroll
    for (int rt = 0; rt < 4; ++rt) {
      f32x4 a0 = zf, a1 = zf;
#pragma unroll
      for (int kt = 0; kt < 4; ++kt) {
        bf16x8 av = *(const bf16x8*)(&A_lds[(rt * 16 + fc) * 136 + kt * 32 + fg * 8]);
        a0 = mfma16(av, BD[0][kt], a0);
        a1 = mfma16(av, BD[1][kt], a1);
      }
#pragma unroll
      for (int r = 0; r < 4; ++r) {
        int node = n0 + rt * 16 + fg * 4 + r;
        if (node < NN) {
          float2 o; o.x = a0[r]; o.y = a1[r];
          *(float2*)(Xd_b + (size_t)node * 128 + ncol0 + 2 * fc) = o;
        }
      }
    }
  }
  // ---- node-MLP layer 1 -> B_lds (plain cols, bias via C-init, relu, RNE) ----
  {
    float b1v0 = nb1[ncol0 + fc], b1v1 = nb1[ncol0 + 16 + fc];
    bf16x8 BN[2][4];
#pragma unroll
    for (int nt = 0; nt < 2; ++nt)
#pragma unroll
      for (int kt = 0; kt < 4; ++kt)
        BN[nt][kt] = *(const bf16x8*)(nw1T + (ncol0 + nt * 16 + fc) * 128 + kt * 32 + fg * 8);
#pragma unroll
    for (int rt = 0; rt < 4; ++rt) {
      f32x4 a0 = {b1v0, b1v0, b1v0, b1v0};
      f32x4 a1 = {b1v1, b1v1, b1v1, b1v1};
#pragma unroll
      for (int kt = 0; kt < 4; ++kt) {
        bf16x8 av = *(const bf16x8*)(&A_lds[(rt * 16 + fc) * 136 + kt * 32 + fg * 8]);
        a0 = mfma16(av, BN[0][kt], a0);
        a1 = mfma16(av, BN[1][kt], a1);
      }
#pragma unroll
      for (int r = 0; r < 4; ++r) {
        int row = rt * 16 + fg * 4 + r;
        B_lds[row * 136 + ncol0 + fc] = (short)f2bf(fmaxf(a0[r], 0.f));
        B_lds[row * 136 + ncol0 + 16 + fc] = (short)f2bf(fmaxf(a1[r], 0.f));
      }
    }
  }
  __syncthreads();

  // ---- node-MLP layer 2 + column-sum ----
  float acc0 = 0.f, acc1 = 0.f;
  {
    float b2v0 = nb2[ncol0 + fc], b2v1 = nb2[ncol0 + 16 + fc];
    bf16x8 BN2[2][4];
#pragma unroll
    for (int nt = 0; nt < 2; ++nt)
#pragma unroll
      for (int kt = 0; kt < 4; ++kt)
        BN2[nt][kt] = *(const bf16x8*)(nw2T + (ncol0 + nt * 16 + fc) * 128 + kt * 32 + fg * 8);
#pragma unroll
    for (int rt = 0; rt < 4; ++rt) {
      f32x4 a0 = {b2v0, b2v0, b2v0, b2v0};
      f32x4 a1 = {b2v1, b2v1, b2v1, b2v1};
#pragma unroll
      for (int kt = 0; kt < 4; ++kt) {
        bf16x8 hv = *(const bf16x8*)(&B_lds[(rt * 16 + fc) * 136 + kt * 32 + fg * 8]);
        a0 = mfma16(hv, BN2[0][kt], a0);
        a1 = mfma16(hv, BN2[1][kt], a1);
      }
#pragma unroll
      for (int r = 0; r < 4; ++r) {
        int node = n0 + rt * 16 + fg * 4 + r;
        if (node < NN) {
          acc0 += fmaxf(a0[r], 0.f);
          acc1 += fmaxf(a1[r], 0.f);
        }
      }
    }
  }
  acc0 += __shfl_xor(acc0, 16); acc0 += __shfl_xor(acc0, 32);
  acc1 += __shfl_xor(acc1, 16); acc1 += __shfl_xor(acc1, 32);
  if (fg == 0) {
    const int stripe = blockIdx.x & (STRIPES - 1);
    float* base = node_acc + ((size_t)b * STRIPES + stripe) * 128;
    atomicAdd(base + ncol0 + fc, acc0);
    atomicAdd(base + ncol0 + 16 + fc, acc1);
  }
}

// edge kernel v3: h1 = relu(Xs[src]+Xd[dst]+E@W1E+b1) with f32 register gather
// (no Gsum LDS, no extra bf16 rounding); m = relu(h1@eW2+b2)*gate
__global__ __launch_bounds__(256, 4) void edge_kernel3(
    const float* __restrict__ Xs, const float* __restrict__ Xd,
    const float* __restrict__ E, const int* __restrict__ edges,
    const short* __restrict__ w1eT, const short* __restrict__ pwT,
    const short* __restrict__ ew2T, const float* __restrict__ eb1,
    const float* __restrict__ eb2, const float* __restrict__ gsp,
    float* __restrict__ edge_acc) {
  __shared__ __align__(16) short h1s[64 * 128];   // swizzled bf16, 16 KB
  __shared__ __align__(16) short E_lds[64 * 40];  // pitch 40 shorts, 5 KB
  __shared__ float gate_lds[64];
  __shared__ __align__(8) int idx_lds[128];

  const int tid = threadIdx.x;
  const int lane = tid & 63;
  const int w = tid >> 6;
  const int fc = lane & 15;
  const int fg = lane >> 4;
  const int ncol0 = w * 32;
  const int b = blockIdx.y;
  const float gs = gsp[0];
  const float* E_b = E + (size_t)b * ME * 16;
  const int* edges_b = edges + (size_t)b * ME * 2;
  const float* Xs_b = Xs + (size_t)b * NN * 128;
  const float* Xd_b = Xd + (size_t)b * NN * 128;
  const f32x4 zf = {0.f, 0.f, 0.f, 0.f};

  // persistent fragments (table-col space; eb1 in hidden space)
  bf16x8 W1E[2], PW[2], B2f[2][4];
  float eb1v[2], eb2v[2];
#pragma unroll
  for (int nt = 0; nt < 2; ++nt) {
    int col = ncol0 + nt * 16 + fc;
    W1E[nt] = *(const bf16x8*)(w1eT + col * 32 + fg * 8);
    PW[nt] = *(const bf16x8*)(pwT + col * 32 + fg * 8);
#pragma unroll
    for (int kt = 0; kt < 4; ++kt)
      B2f[nt][kt] = *(const bf16x8*)(ew2T + col * 128 + kt * 32 + fg * 8);
    eb1v[nt] = eb1[ncol0 + 2 * fc + nt];  // hid(col)
    eb2v[nt] = eb2[col];
  }

  // zero E_lds k=16..31 once (never rewritten)
  if (tid < 64) {
    uint4 z = {0, 0, 0, 0};
    *(uint4*)(&E_lds[tid * 40 + 16]) = z;
    *(uint4*)(&E_lds[tid * 40 + 24]) = z;
  }

  const int et = tid >> 2, eq = tid & 3;  // E staging: 4 threads/edge
  const int cb = ncol0 + 2 * fc;          // this thread's hidden col pair
  float accm0 = 0.f, accm1 = 0.f, accp0 = 0.f, accp1 = 0.f, accg = 0.f;

  for (int it = 0; it < NT2; ++it) {
    const int e0 = (blockIdx.x * NT2 + it) * 64;
    // ---- stage: idx, E (bf16 RNE), gate ----
    if (tid < 128) idx_lds[tid] = edges_b[(size_t)e0 * 2 + tid];
    {
      float4 fe = ((const float4*)E_b)[(size_t)(e0 + et) * 4 + eq];
      uint2 ue;
      ue.x = (unsigned)f2bf(fe.x) | ((unsigned)f2bf(fe.y) << 16);
      ue.y = (unsigned)f2bf(fe.z) | ((unsigned)f2bf(fe.w) << 16);
      *(uint2*)(&E_lds[et * 40 + eq * 4]) = ue;
      if (eq == 0) gate_lds[et] = fminf(fmaxf(1.f + gs * fe.z, 0.f), 3.f);
    }
    __syncthreads();

    // ---- phase 1: per-rt {prefetch rt+1 gathers; E-MFMA; combine f32; h1->LDS} ----
    float2 gsv[2][4], gdv[2][4];
#define LOAD_RT(P, RT)                                                        \
    {                                                                         \
      _Pragma("unroll")                                                       \
      for (int r = 0; r < 4; ++r) {                                           \
        int row = (RT) * 16 + fg * 4 + r;                                     \
        int2 sd = *(const int2*)(&idx_lds[2 * row]);                          \
        gsv[P][r] = *(const float2*)(Xs_b + (size_t)sd.x * 128 + cb);         \
        gdv[P][r] = *(const float2*)(Xd_b + (size_t)sd.y * 128 + cb);         \
      }                                                                       \
    }
    LOAD_RT(0, 0)
#pragma unroll
    for (int rt = 0; rt < 4; ++rt) {
      if (rt < 3) LOAD_RT((rt + 1) & 1, rt + 1)
      bf16x8 Ef = *(const bf16x8*)(&E_lds[(rt * 16 + fc) * 40 + fg * 8]);
      f32x4 a0 = {eb1v[0], eb1v[0], eb1v[0], eb1v[0]};
      f32x4 a1 = {eb1v[1], eb1v[1], eb1v[1], eb1v[1]};
      a0 = mfma16(Ef, W1E[0], a0);
      a1 = mfma16(Ef, W1E[1], a1);
      f32x4 q0 = mfma16(Ef, PW[0], zf);
      f32x4 q1 = mfma16(Ef, PW[1], zf);
#pragma unroll
      for (int r = 0; r < 4; ++r) {
        int row = rt * 16 + fg * 4 + r;
        float g = gate_lds[row];
        accp0 += q0[r] * g;
        accp1 += q1[r] * g;
        float v0 = fmaxf(a0[r] + gsv[rt & 1][r].x + gdv[rt & 1][r].x, 0.f);
        float v1 = fmaxf(a1[r] + gsv[rt & 1][r].y + gdv[rt & 1][r].y, 0.f);
        int di = row * 64 + ((w * 16 + fc) ^ ((row & 7) << 2));
        ((unsigned*)h1s)[di] = (unsigned)f2bf(v0) | ((unsigned)f2bf(v1) << 16);
      }
    }
#undef LOAD_RT
    __syncthreads();

    // ---- phase 2: layer 2 (+bias via C-init) ----
    if (w == 0) accg += gate_lds[lane];
#pragma unroll
    for (int rt = 0; rt < 4; ++rt) {
      const int arow = rt * 16 + fc;
      f32x4 a0 = {eb2v[0], eb2v[0], eb2v[0], eb2v[0]};
      f32x4 a1 = {eb2v[1], eb2v[1], eb2v[1], eb2v[1]};
#pragma unroll
      for (int kt = 0; kt < 4; ++kt) {
        bf16x8 hv = *(const bf16x8*)(&h1s[arow * 128 + ((kt * 32 + fg * 8) ^ ((arow & 7) << 3))]);
        a0 = mfma16(hv, B2f[0][kt], a0);
        a1 = mfma16(hv, B2f[1][kt], a1);
      }
#pragma unroll
      for (int r = 0; r < 4; ++r) {
        int row = rt * 16 + fg * 4 + r;
        float g = gate_lds[row];
        accm0 += fmaxf(a0[r], 0.f) * g;
        accm1 += fmaxf(a1[r], 0.f) * g;
      }
    }
    __syncthreads();
  }

  // ---- reduce over fg, striped atomics ----
  accm0 += __shfl_xor(accm0, 16); accm0 += __shfl_xor(accm0, 32);
  accm1 += __shfl_xor(accm1, 16); accm1 += __shfl_xor(accm1, 32);
  accp0 += __shfl_xor(accp0, 16); accp0 += __shfl_xor(accp0, 32);
  accp1 += __shfl_xor(accp1, 16); accp1 += __shfl_xor(accp1, 32);
  const int stripe = blockIdx.x & (STRIPES - 1);
  float* base = edge_acc + ((size_t)b * STRIPES + stripe) * 264;
  if (fg == 0) {
    atomicAdd(base + ncol0 + fc, accm0);
    atomicAdd(base + ncol0 + 16 + fc, accm1);
    atomicAdd(base + 128 + ncol0 + fc, accp0);
    atomicAdd(base + 128 + ncol0 + 16 + fc, accp1);
  }
  if (w == 0) {
#pragma unroll
    for (int off = 1; off < 64; off <<= 1) accg += __shfl_xor(accg, off);
    if (lane == 0) atomicAdd(base + 256, accg);
  }
}

// ================= fallback path (round-3, known-good) =================

__global__ void prep_w_fb(const float* __restrict__ eW1, const float* __restrict__ eW2,
                          const float* __restrict__ nW1, const float* __restrict__ nW2,
                          const float* __restrict__ pW,
                          short* __restrict__ ew1T, short* __restrict__ ew2T,
                          short* __restrict__ nw1T, short* __restrict__ nw2T,
                          short* __restrict__ pwT) {
  int c = blockIdx.x;
  int t = threadIdx.x;
  for (int k = t; k < 288; k += 256)
    ew1T[c * 288 + k] = (k < 272) ? (short)f2bf(eW1[(size_t)k * 128 + c]) : (short)0;
  if (t < 128) {
    ew2T[c * 128 + t] = (short)f2bf(eW2[(size_t)t * 128 + c]);
    nw1T[c * 128 + t] = (short)f2bf(nW1[(size_t)t * 128 + c]);
    nw2T[c * 128 + t] = (short)f2bf(nW2[(size_t)t * 128 + c]);
  }
  if (t < 32) pwT[c * 32 + t] = (t < 16) ? (short)f2bf(pW[(size_t)t * 128 + c]) : (short)0;
}

template<bool WRITEBF>
__global__ __launch_bounds__(256, 2) void node_kernel_fb(
    const float* __restrict__ X, short* __restrict__ Xbf,
    const short* __restrict__ nw1T, const short* __restrict__ nw2T,
    const float* __restrict__ nb1, const float* __restrict__ nb2,
    float* __restrict__ node_acc) {
  __shared__ __align__(16) short A_lds[64 * 136];
  __shared__ __align__(16) short h1_lds[64 * 136];
  const int tid = threadIdx.x;
  const int lane = tid & 63;
  const int w = tid >> 6;
  const int fc = lane & 15;
  const int fg = lane >> 4;
  const int ncol0 = w * 32;
  const int b = blockIdx.y;
  const float* X_b = X + (size_t)b * NN * 128;
  short* Xbf_b = Xbf + (size_t)b * NN * 128;

  bf16x8 B1[2][4], B2[2][4];
  float b1v[2], b2v[2];
#pragma unroll
  for (int nt = 0; nt < 2; ++nt) {
    int col = ncol0 + nt * 16 + fc;
#pragma unroll
    for (int kt = 0; kt < 4; ++kt) {
      B1[nt][kt] = *reinterpret_cast<const bf16x8*>(nw1T + col * 128 + kt * 32 + fg * 8);
      B2[nt][kt] = *reinterpret_cast<const bf16x8*>(nw2T + col * 128 + kt * 32 + fg * 8);
    }
    b1v[nt] = nb1[col];
    b2v[nt] = nb2[col];
  }

  const int n0 = blockIdx.x * 64;
#pragma unroll
  for (int p = 0; p < 8; ++p) {
    int slot = p * 256 + tid;
    int row = slot >> 5, chunk = slot & 31;
    int node = n0 + row;
    ushort4 v = {0, 0, 0, 0};
    if (node < NN) {
      float4 f = *reinterpret_cast<const float4*>(X_b + (size_t)node * 128 + chunk * 4);
      v.x = f2bf(f.x); v.y = f2bf(f.y); v.z = f2bf(f.z); v.w = f2bf(f.w);
      if (WRITEBF) *reinterpret_cast<ushort4*>(Xbf_b + (size_t)node * 128 + chunk * 4) = v;
    }
    *reinterpret_cast<ushort4*>(&A_lds[row * 136 + chunk * 4]) = v;
  }
  __syncthreads();

  f32x4 zf = {0.f, 0.f, 0.f, 0.f};
  float acc0 = 0.f, acc1 = 0.f;
#pragma unroll
  for (int rt = 0; rt < 4; ++rt) {
    const short* arow = &A_lds[(rt * 16 + fc) * 136 + fg * 8];
    f32x4 a0 = zf, a1 = zf;
#pragma unroll
    for (int kt = 0; kt < 4; ++kt) {
      bf16x8 av = *reinterpret_cast<const bf16x8*>(arow + kt * 32);
      a0 = mfma16(av, B1[0][kt], a0);
      a1 = mfma16(av, B1[1][kt], a1);
    }
#pragma unroll
    for (int r = 0; r < 4; ++r) {
      int row = rt * 16 + fg * 4 + r;
      h1_lds[row * 136 + ncol0 + fc] = (short)f2bf(fmaxf(a0[r] + b1v[0], 0.f));
      h1_lds[row * 136 + ncol0 + 16 + fc] = (short)f2bf(fmaxf(a1[r] + b1v[1], 0.f));
    }
  }
  __syncthreads();
#pragma unroll
  for (int rt = 0; rt < 4; ++rt) {
    const short* hrow = &h1_lds[(rt * 16 + fc) * 136 + fg * 8];
    f32x4 a0 = zf, a1 = zf;
#pragma unroll
    for (int kt = 0; kt < 4; ++kt) {
      bf16x8 hv = *reinterpret_cast<const bf16x8*>(hrow + kt * 32);
      a0 = mfma16(hv, B2[0][kt], a0);
      a1 = mfma16(hv, B2[1][kt], a1);
    }
#pragma unroll
    for (int r = 0; r < 4; ++r) {
      int row = n0 + rt * 16 + fg * 4 + r;
      if (row < NN) {
        acc0 += fmaxf(a0[r] + b2v[0], 0.f);
        acc1 += fmaxf(a1[r] + b2v[1], 0.f);
      }
    }
  }
  acc0 += __shfl_xor(acc0, 16); acc0 += __shfl_xor(acc0, 32);
  acc1 += __shfl_xor(acc1, 16); acc1 += __shfl_xor(acc1, 32);
  if (fg == 0) {
    const int stripe = blockIdx.x & (STRIPES - 1);
    float* base = node_acc + ((size_t)b * STRIPES + stripe) * 128;
    atomicAdd(base + ncol0 + fc, acc0);
    atomicAdd(base + ncol0 + 16 + fc, acc1);
  }
}

template<bool XBF>
__global__ __launch_bounds__(256, 2) void edge_kernel_fb(
    const short* __restrict__ Xbf, const float* __restrict__ X,
    const float* __restrict__ E, const int* __restrict__ edges,
    const short* __restrict__ ew1T, const short* __restrict__ ew2T,
    const short* __restrict__ pwT, const float* __restrict__ eb1,
    const float* __restrict__ eb2, const float* __restrict__ gsp,
    float* __restrict__ edge_acc) {
  __shared__ __align__(16) short A_lds[64 * 296];
  __shared__ __align__(16) short h1_lds[64 * 136];
  __shared__ float gate_lds[2][64];
  __shared__ int idx_lds[2][128];

  const int tid = threadIdx.x;
  const int lane = tid & 63;
  const int w = tid >> 6;
  const int fc = lane & 15;
  const int fg = lane >> 4;
  const int ncol0 = w * 32;
  const int b = blockIdx.y;

  const float gs = gsp[0];
  const float* E_b = E + (size_t)b * ME * 16;
  const int* edges_b = edges + (size_t)b * ME * 2;
  const short* Xbf_b = Xbf + (size_t)b * NN * 128;
  const float* X_b = X + (size_t)b * NN * 128;
  const int tile0 = blockIdx.x * NT_FB;

  bf16x8 B1[2][9], B2[2][4], PWf[2];
  float eb1v[2], eb2v[2];
#pragma unroll
  for (int nt = 0; nt < 2; ++nt) {
    int col = ncol0 + nt * 16 + fc;
#pragma unroll
    for (int kt = 0; kt < 9; ++kt)
      B1[nt][kt] = *reinterpret_cast<const bf16x8*>(ew1T + col * 288 + kt * 32 + fg * 8);
#pragma unroll
    for (int kt = 0; kt < 4; ++kt)
      B2[nt][kt] = *reinterpret_cast<const bf16x8*>(ew2T + col * 128 + kt * 32 + fg * 8);
    PWf[nt] = *reinterpret_cast<const bf16x8*>(pwT + col * 32 + fg * 8);
    eb1v[nt] = eb1[col];
    eb2v[nt] = eb2[col];
  }

  const int grow = tid >> 1;
  const int ge = grow & 63;
  const int gsd = grow >> 6;
  const int gpos = (ge << 1) | gsd;
  const int ghalf = tid & 1;
  const int et = tid >> 2, q = tid & 3;

#define GATHER8(node, v0, v1, v2, v3, v4, v5, v6, v7)                                   \
  if (XBF) {                                                                            \
    const bf16x8* gp = reinterpret_cast<const bf16x8*>(Xbf_b + (size_t)(node)*128 + ghalf*64); \
    v0 = gp[0]; v1 = gp[1]; v2 = gp[2]; v3 = gp[3];                                     \
    v4 = gp[4]; v5 = gp[5]; v6 = gp[6]; v7 = gp[7];                                     \
  } else {                                                                              \
    const float4* gp = reinterpret_cast<const float4*>(X_b + (size_t)(node)*128 + ghalf*64); \
    v0 = pack2(gp[0], gp[1]);  v1 = pack2(gp[2], gp[3]);                                \
    v2 = pack2(gp[4], gp[5]);  v3 = pack2(gp[6], gp[7]);                                \
    v4 = pack2(gp[8], gp[9]);  v5 = pack2(gp[10], gp[11]);                              \
    v6 = pack2(gp[12], gp[13]); v7 = pack2(gp[14], gp[15]);                             \
  }

#define STORE8(v0, v1, v2, v3, v4, v5, v6, v7)                                          \
  {                                                                                     \
    bf16x8* aw8 = reinterpret_cast<bf16x8*>(&A_lds[ge * 296 + gsd * 128 + ghalf * 64]); \
    aw8[0] = v0; aw8[1] = v1; aw8[2] = v2; aw8[3] = v3;                                 \
    aw8[4] = v4; aw8[5] = v5; aw8[6] = v6; aw8[7] = v7;                                 \
  }

  if (tid < 64) {
    bf16x8 z = {0, 0, 0, 0, 0, 0, 0, 0};
    *reinterpret_cast<bf16x8*>(&A_lds[tid * 296 + 272]) = z;
    *reinterpret_cast<bf16x8*>(&A_lds[tid * 296 + 280]) = z;
  }
  {
    const int e0 = tile0 * 64;
    int node = edges_b[(size_t)e0 * 2 + gpos];
    bf16x8 s0, s1, s2, s3, s4, s5, s6, s7;
    GATHER8(node, s0, s1, s2, s3, s4, s5, s6, s7);
    STORE8(s0, s1, s2, s3, s4, s5, s6, s7);
    float4 ev = *reinterpret_cast<const float4*>(E_b + (size_t)e0 * 16 + tid * 4);
    ushort4 evb; evb.x = f2bf(ev.x); evb.y = f2bf(ev.y); evb.z = f2bf(ev.z); evb.w = f2bf(ev.w);
    *reinterpret_cast<ushort4*>(&A_lds[et * 296 + 256 + q * 4]) = evb;
    if (q == 0) gate_lds[0][et] = fminf(fmaxf(1.f + gs * ev.z, 0.f), 3.f);
    if (tid < 128) idx_lds[1][tid] = edges_b[(size_t)(tile0 + 1) * 64 * 2 + tid];
  }
  __syncthreads();

  float accm0 = 0.f, accm1 = 0.f, accp0 = 0.f, accp1 = 0.f, accg = 0.f;
  const f32x4 zf = {0.f, 0.f, 0.f, 0.f};

  for (int it = 0; it < NT_FB; ++it) {
    const int cur = it & 1, nxt = (it + 1) & 1;
    const bool hasn1 = (it + 1 < NT_FB);
    const bool hasn2 = (it + 2 < NT_FB);
    const int e0n = (hasn1 ? (tile0 + it + 1) : tile0) * 64;
    const int e0n2 = (hasn2 ? (tile0 + it + 2) : tile0) * 64;

    float4 epre = *reinterpret_cast<const float4*>(E_b + (size_t)e0n * 16 + tid * 4);
    int idxpre = 0;
    if (tid < 128) idxpre = edges_b[(size_t)e0n2 * 2 + tid];
    const int node = idx_lds[nxt][gpos];
    bf16x8 p0v, p1v, p2v, p3v, p4v, p5v, p6v, p7v;
    GATHER8(node, p0v, p1v, p2v, p3v, p4v, p5v, p6v, p7v);

#pragma unroll
    for (int rt = 0; rt < 4; ++rt) {
      const short* arow = &A_lds[(rt * 16 + fc) * 296 + fg * 8];
      f32x4 a0 = zf, a1 = zf;
#pragma unroll
      for (int kt = 0; kt < 9; ++kt) {
        bf16x8 av = *reinterpret_cast<const bf16x8*>(arow + kt * 32);
        a0 = mfma16(av, B1[0][kt], a0);
        a1 = mfma16(av, B1[1][kt], a1);
      }
      bf16x8 av8 = *reinterpret_cast<const bf16x8*>(arow + 256);
      f32x4 q0 = mfma16(av8, PWf[0], zf);
      f32x4 q1 = mfma16(av8, PWf[1], zf);
#pragma unroll
      for (int r = 0; r < 4; ++r) {
        int row = rt * 16 + fg * 4 + r;
        float g = gate_lds[cur][row];
        accp0 += q0[r] * g;
        accp1 += q1[r] * g;
        h1_lds[row * 136 + ncol0 + fc] = (short)f2bf(fmaxf(a0[r] + eb1v[0], 0.f));
        h1_lds[row * 136 + ncol0 + 16 + fc] = (short)f2bf(fmaxf(a1[r] + eb1v[1], 0.f));
      }
    }
    __syncthreads();

    if (hasn1) {
      STORE8(p0v, p1v, p2v, p3v, p4v, p5v, p6v, p7v);
      ushort4 evb; evb.x = f2bf(epre.x); evb.y = f2bf(epre.y); evb.z = f2bf(epre.z); evb.w = f2bf(epre.w);
      *reinterpret_cast<ushort4*>(&A_lds[et * 296 + 256 + q * 4]) = evb;
      if (q == 0) gate_lds[nxt][et] = fminf(fmaxf(1.f + gs * epre.z, 0.f), 3.f);
      if (tid < 128) idx_lds[cur][tid] = idxpre;
    }

    if (w == 0) accg += gate_lds[cur][lane];
#pragma unroll
    for (int rt = 0; rt < 4; ++rt) {
      const short* hrow = &h1_lds[(rt * 16 + fc) * 136 + fg * 8];
      f32x4 a0 = zf, a1 = zf;
#pragma unroll
      for (int kt = 0; kt < 4; ++kt) {
        bf16x8 hv = *reinterpret_cast<const bf16x8*>(hrow + kt * 32);
        a0 = mfma16(hv, B2[0][kt], a0);
        a1 = mfma16(hv, B2[1][kt], a1);
      }
#pragma unroll
      for (int r = 0; r < 4; ++r) {
        int row = rt * 16 + fg * 4 + r;
        float g = gate_lds[cur][row];
        accm0 += fmaxf(a0[r] + eb2v[0], 0.f) * g;
        accm1 += fmaxf(a1[r] + eb2v[1], 0.f) * g;
      }
    }
    __syncthreads();
  }

  accm0 += __shfl_xor(accm0, 16); accm0 += __shfl_xor(accm0, 32);
  accm1 += __shfl_xor(accm1, 16); accm1 += __shfl_xor(accm1, 32);
  accp0 += __shfl_xor(accp0, 16); accp0 += __shfl_xor(accp0, 32);
  accp1 += __shfl_xor(accp1, 16); accp1 += __shfl_xor(accp1, 32);
  const int stripe = blockIdx.x & (STRIPES - 1);
  float* base = edge_acc + ((size_t)b * STRIPES + stripe) * 264;
  if (fg == 0) {
    atomicAdd(base + ncol0 + fc, accm0);
    atomicAdd(base + ncol0 + 16 + fc, accm1);
    atomicAdd(base + 128 + ncol0 + fc, accp0);
    atomicAdd(base + 128 + ncol0 + 16 + fc, accp1);
  }
  if (w == 0) {
#pragma unroll
    for (int off = 1; off < 64; off <<= 1) accg += __shfl_xor(accg, off);
    if (lane == 0) atomicAdd(base + 256, accg);
  }
#undef GATHER8
#undef STORE8
}

// ---------------- final combine + readout head (exact f32, both paths) ----------------

__global__ void final_kernel(const float* __restrict__ edge_acc, const float* __restrict__ node_acc,
                             const float* __restrict__ pb, const float* __restrict__ rW1,
                             const float* __restrict__ rb1, const float* __restrict__ rW2,
                             const float* __restrict__ rb2, float* __restrict__ out) {
  int b = blockIdx.x;
  int j = threadIdx.x;  // 0..127
  __shared__ float feat[256];
  __shared__ float h[64];
  const float* ea = edge_acc + (size_t)b * STRIPES * 264;
  const float* na = node_acc + (size_t)b * STRIPES * 128;
  float ms = 0.f, ps = 0.f, hs = 0.f, gsum = 0.f;
  for (int s = 0; s < STRIPES; ++s) {
    ms += ea[s * 264 + j];
    ps += ea[s * 264 + 128 + j];
    hs += na[s * 128 + j];
    gsum += ea[s * 264 + 256];
  }
  feat[j] = (hs + 2.f * ms) * (1.f / (float)NN);
  feat[128 + j] = (ps + gsum * pb[j]) / ((float)ME + 1e-6f);
  __syncthreads();
  if (j < 64) {
    float a = rb1[j];
    for (int i = 0; i < 256; ++i) a += feat[i] * rW1[i * 64 + j];
    h[j] = fmaxf(a, 0.f);
  }
  __syncthreads();
  if (j < 2) {
    float a = rb2[j];
    for (int i = 0; i < 64; ++i) a += h[i] * rW2[i * 2 + j];
    out[b * 2 + j] = a;
  }
}

// ---------------- host ----------------

extern "C" void kernel_launch(void* const* d_in, const int* in_sizes, int n_in,
                              void* d_out, int out_size, void* d_ws, size_t ws_size,
                              hipStream_t stream) {
  const float* X = (const float*)d_in[0];
  const float* E = (const float*)d_in[1];
  const int* edges = (const int*)d_in[2];
  const float* nW1 = (const float*)d_in[3];
  const float* nb1 = (const float*)d_in[4];
  const float* nW2 = (const float*)d_in[5];
  const float* nb2 = (const float*)d_in[6];
  const float* eW1 = (const float*)d_in[7];
  const float* eb1 = (const float*)d_in[8];
  const float* eW2 = (const float*)d_in[9];
  const float* eb2 = (const float*)d_in[10];
  const float* pW = (const float*)d_in[11];
  const float* pb = (const float*)d_in[12];
  const float* rW1 = (const float*)d_in[13];
  const float* rb1 = (const float*)d_in[14];
  const float* rW2 = (const float*)d_in[15];
  const float* rb2 = (const float*)d_in[16];
  const float* gscale = (const float*)d_in[17];
  float* out = (float*)d_out;

  char* ws = (char*)d_ws;
  size_t off = 0;
  auto alloc = [&](size_t sz) -> void* {
    void* p = ws + off;
    off = (off + sz + 255) & ~(size_t)255;
    return p;
  };
  size_t acc_floats = (size_t)NB * STRIPES * 264 + (size_t)NB * STRIPES * 128;

  // ---- new-path layout (f32 Xs/Xd) ----
  short* es1T = (short*)alloc(128 * 128 * 2);
  short* ed1T = (short*)alloc(128 * 128 * 2);
  short* w1eT = (short*)alloc(128 * 32 * 2);
  short* ew2T = (short*)alloc(128 * 128 * 2);
  short* nw1T = (short*)alloc(128 * 128 * 2);
  short* nw2T = (short*)alloc(128 * 128 * 2);
  short* pwT  = (short*)alloc(128 * 32 * 2);
  float* acc  = (float*)alloc(acc_floats * 4);
  float* Xs   = (float*)alloc((size_t)NB * NN * 128 * 4);
  float* Xd   = (float*)alloc((size_t)NB * NN * 128 * 4);
  bool fit = off <= ws_size;

  if (fit) {
    float* edge_acc = acc;
    float* node_acc = acc + (size_t)NB * STRIPES * 264;
    hipMemsetAsync(acc, 0, acc_floats * 4, stream);
    prep_w2<<<dim3(128), dim3(256), 0, stream>>>(eW1, eW2, nW1, nW2, pW,
                                                 es1T, ed1T, w1eT, ew2T, nw1T, nw2T, pwT);
    node_prep<<<dim3(313, 2), dim3(256), 0, stream>>>(X, nw1T, nw2T, es1T, ed1T,
                                                      nb1, nb2, Xs, Xd, node_acc);
    edge_kernel3<<<dim3(1000, 2), dim3(256), 0, stream>>>(Xs, Xd, E, edges, w1eT, pwT,
                                                          ew2T, eb1, eb2, gscale, edge_acc);
    final_kernel<<<dim3(NB), dim3(128), 0, stream>>>(edge_acc, node_acc, pb, rW1, rb1, rW2, rb2, out);
    return;
  }

  // ---- fallback: round-3 layout & kernels ----
  off = 0;
  short* ew1T_f = (short*)alloc(288 * 128 * 2);
  short* ew2T_f = (short*)alloc(128 * 128 * 2);
  short* nw1T_f = (short*)alloc(128 * 128 * 2);
  short* nw2T_f = (short*)alloc(128 * 128 * 2);
  short* pwT_f  = (short*)alloc(32 * 128 * 2);
  float* acc_f  = (float*)alloc(acc_floats * 4);
  float* edge_acc = acc_f;
  float* node_acc = acc_f + (size_t)NB * STRIPES * 264;
  size_t xbf_bytes = (size_t)NB * NN * 128 * 2;
  size_t off_before_xbf = off;
  short* Xbf = (short*)alloc(xbf_bytes);
  bool use_xbf = (off_before_xbf + xbf_bytes) <= ws_size;

  hipMemsetAsync(acc_f, 0, acc_floats * 4, stream);
  prep_w_fb<<<dim3(128), dim3(256), 0, stream>>>(eW1, eW2, nW1, nW2, pW,
                                                 ew1T_f, ew2T_f, nw1T_f, nw2T_f, pwT_f);
  if (use_xbf) {
    node_kernel_fb<true><<<dim3(313, 2), dim3(256), 0, stream>>>(X, Xbf, nw1T_f, nw2T_f, nb1, nb2, node_acc);
    edge_kernel_fb<true><<<dim3(625, 2), dim3(256), 0, stream>>>(
        Xbf, X, E, edges, ew1T_f, ew2T_f, pwT_f, eb1, eb2, gscale, edge_acc);
  } else {
    node_kernel_fb<false><<<dim3(313, 2), dim3(256), 0, stream>>>(X, Xbf, nw1T_f, nw2T_f, nb1, nb2, node_acc);
    edge_kernel_fb<false><<<dim3(625, 2), dim3(256), 0, stream>>>(
        Xbf, X, E, edges, ew1T_f, ew2T_f, pwT_f, eb1, eb2, gscale, edge_acc);
  }
  final_kernel<<<dim3(NB), dim3(128), 0, stream>>>(edge_acc, node_acc, pb, rW1, rb1, rW2, rb2, out);
}

// Round 7
// 334.621 us; speedup vs baseline: 1.1806x; 1.1806x over previous
//
#include <hip/hip_runtime.h>
#include <hip/hip_fp16.h>

typedef short bf16x8 __attribute__((ext_vector_type(8)));
typedef float f32x4 __attribute__((ext_vector_type(4)));

#define NB 2
#define NN 20000
#define ME 320000
#define STRIPES 64
#define NT_FB 8  // tiles per block, fallback edge kernel
#define NT2 5    // tiles per block, new edge kernel (5000 tiles / 1000 blocks)

__device__ __forceinline__ unsigned short f2bf(float f) {
  union { float f; unsigned int u; } v; v.f = f;
  unsigned int r = (v.u + 0x7FFFu + ((v.u >> 16) & 1u)) >> 16;  // RNE
  return (unsigned short)r;
}

__device__ __forceinline__ unsigned short f2h(float f) {
  return __half_as_ushort(__float2half_rn(f));  // fp16 RNE
}

__device__ __forceinline__ float2 h2f2(unsigned u) {
  union { unsigned u; __half2 h; } v; v.u = u;
  return make_float2(__low2float(v.h), __high2float(v.h));
}

__device__ __forceinline__ bf16x8 pack2(float4 a, float4 b) {
  bf16x8 v;
  v[0]=(short)f2bf(a.x); v[1]=(short)f2bf(a.y); v[2]=(short)f2bf(a.z); v[3]=(short)f2bf(a.w);
  v[4]=(short)f2bf(b.x); v[5]=(short)f2bf(b.y); v[6]=(short)f2bf(b.z); v[7]=(short)f2bf(b.w);
  return v;
}

__device__ __forceinline__ f32x4 mfma16(bf16x8 a, bf16x8 b, f32x4 c) {
  return __builtin_amdgcn_mfma_f32_16x16x32_bf16(a, b, c, 0, 0, 0);
}

// hidden-col interleave: table col c holds hidden column hid(c) = (c&~31) + 2*(c&15) + ((c>>4)&1),
// so a wave's frag pair (nt=0,nt=1) at lane fc covers adjacent hidden cols (2fc, 2fc+1).
__device__ __forceinline__ int hidcol(int c) {
  return (c & ~31) + 2 * (c & 15) + ((c >> 4) & 1);
}

// ================= new path =================

__global__ void prep_w2(const float* __restrict__ eW1, const float* __restrict__ eW2,
                        const float* __restrict__ nW1, const float* __restrict__ nW2,
                        const float* __restrict__ pW,
                        short* __restrict__ es1T, short* __restrict__ ed1T,
                        short* __restrict__ w1eT, short* __restrict__ ew2T,
                        short* __restrict__ nw1T, short* __restrict__ nw2T,
                        short* __restrict__ pwT) {
  int c = blockIdx.x;   // 0..127 table column
  int t = threadIdx.x;  // 256
  int hc = hidcol(c);
  if (t < 128) {
    es1T[c * 128 + t] = (short)f2bf(eW1[(size_t)t * 128 + hc]);
    ed1T[c * 128 + t] = (short)f2bf(eW1[(size_t)(128 + t) * 128 + hc]);
    ew2T[c * 128 + t] = (short)f2bf(eW2[(size_t)t * 128 + c]);
    nw1T[c * 128 + t] = (short)f2bf(nW1[(size_t)t * 128 + c]);
    nw2T[c * 128 + t] = (short)f2bf(nW2[(size_t)t * 128 + c]);
  }
  if (t < 32) {
    w1eT[c * 32 + t] = (t < 16) ? (short)f2bf(eW1[(size_t)(256 + t) * 128 + hc]) : (short)0;
    pwT[c * 32 + t]  = (t < 16) ? (short)f2bf(pW[(size_t)t * 128 + c]) : (short)0;
  }
}

// node_prep: per 64-node tile, stage X once; emit fp16 Xs = X@eW1[0:128] (hidden-linear
// cols), fp16 Xd = X@eW1[128:256], and the node-MLP Hx column-sums.
__global__ __launch_bounds__(256, 4) void node_prep(
    const float* __restrict__ X,
    const short* __restrict__ nw1T, const short* __restrict__ nw2T,
    const short* __restrict__ es1T, const short* __restrict__ ed1T,
    const float* __restrict__ nb1, const float* __restrict__ nb2,
    unsigned short* __restrict__ Xs, unsigned short* __restrict__ Xd,
    float* __restrict__ node_acc) {
  __shared__ __align__(16) short A_lds[64 * 136];
  __shared__ __align__(16) short B_lds[64 * 136];
  const int tid = threadIdx.x;
  const int lane = tid & 63;
  const int w = tid >> 6;
  const int fc = lane & 15;
  const int fg = lane >> 4;
  const int ncol0 = w * 32;
  const int b = blockIdx.y;
  const int n0 = blockIdx.x * 64;
  const float* X_b = X + (size_t)b * NN * 128;
  unsigned short* Xs_b = Xs + (size_t)b * NN * 128;
  unsigned short* Xd_b = Xd + (size_t)b * NN * 128;
  const f32x4 zf = {0.f, 0.f, 0.f, 0.f};

  // stage X tile (bf16, RNE)
#pragma unroll
  for (int p = 0; p < 8; ++p) {
    int slot = p * 256 + tid;
    int row = slot >> 5, chunk = slot & 31;
    int node = n0 + row;
    uint2 v = {0, 0};
    if (node < NN) {
      float4 f = *(const float4*)(X_b + (size_t)node * 128 + chunk * 4);
      v.x = (unsigned)f2bf(f.x) | ((unsigned)f2bf(f.y) << 16);
      v.y = (unsigned)f2bf(f.z) | ((unsigned)f2bf(f.w) << 16);
    }
    *(uint2*)(&A_lds[row * 136 + chunk * 4]) = v;
  }
  __syncthreads();

  // ---- GEMM-S -> direct fp16 store (hidden-linear: cols ncol0+2fc, +1) ----
  {
    bf16x8 BS[2][4];
#pragma unroll
    for (int nt = 0; nt < 2; ++nt)
#pragma unroll
      for (int kt = 0; kt < 4; ++kt)
        BS[nt][kt] = *(const bf16x8*)(es1T + (ncol0 + nt * 16 + fc) * 128 + kt * 32 + fg * 8);
#pragma unroll
    for (int rt = 0; rt < 4; ++rt) {
      f32x4 a0 = zf, a1 = zf;
#pragma unroll
      for (int kt = 0; kt < 4; ++kt) {
        bf16x8 av = *(const bf16x8*)(&A_lds[(rt * 16 + fc) * 136 + kt * 32 + fg * 8]);
        a0 = mfma16(av, BS[0][kt], a0);
        a1 = mfma16(av, BS[1][kt], a1);
      }
#pragma unroll
      for (int r = 0; r < 4; ++r) {
        int node = n0 + rt * 16 + fg * 4 + r;
        if (node < NN) {
          unsigned o = (unsigned)f2h(a0[r]) | ((unsigned)f2h(a1[r]) << 16);
          *(unsigned*)(Xs_b + (size_t)node * 128 + ncol0 + 2 * fc) = o;
        }
      }
    }
  }
  // ---- GEMM-D -> direct fp16 store ----
  {
    bf16x8 BD[2][4];
#pragma unroll
    for (int nt = 0; nt < 2; ++nt)
#pragma unroll
      for (int kt = 0; kt < 4; ++kt)
        BD[nt][kt] = *(const bf16x8*)(ed1T + (ncol0 + nt * 16 + fc) * 128 + kt * 32 + fg * 8);
#pragma unroll
    for (int rt = 0; rt < 4; ++rt) {
      f32x4 a0 = zf, a1 = zf;
#pragma unroll
      for (int kt = 0; kt < 4; ++kt) {
        bf16x8 av = *(const bf16x8*)(&A_lds[(rt * 16 + fc) * 136 + kt * 32 + fg * 8]);
        a0 = mfma16(av, BD[0][kt], a0);
        a1 = mfma16(av, BD[1][kt], a1);
      }
#pragma unroll
      for (int r = 0; r < 4; ++r) {
        int node = n0 + rt * 16 + fg * 4 + r;
        if (node < NN) {
          unsigned o = (unsigned)f2h(a0[r]) | ((unsigned)f2h(a1[r]) << 16);
          *(unsigned*)(Xd_b + (size_t)node * 128 + ncol0 + 2 * fc) = o;
        }
      }
    }
  }
  // ---- node-MLP layer 1 -> B_lds (plain cols, bias via C-init, relu, RNE) ----
  {
    float b1v0 = nb1[ncol0 + fc], b1v1 = nb1[ncol0 + 16 + fc];
    bf16x8 BN[2][4];
#pragma unroll
    for (int nt = 0; nt < 2; ++nt)
#pragma unroll
      for (int kt = 0; kt < 4; ++kt)
        BN[nt][kt] = *(const bf16x8*)(nw1T + (ncol0 + nt * 16 + fc) * 128 + kt * 32 + fg * 8);
#pragma unroll
    for (int rt = 0; rt < 4; ++rt) {
      f32x4 a0 = {b1v0, b1v0, b1v0, b1v0};
      f32x4 a1 = {b1v1, b1v1, b1v1, b1v1};
#pragma unroll
      for (int kt = 0; kt < 4; ++kt) {
        bf16x8 av = *(const bf16x8*)(&A_lds[(rt * 16 + fc) * 136 + kt * 32 + fg * 8]);
        a0 = mfma16(av, BN[0][kt], a0);
        a1 = mfma16(av, BN[1][kt], a1);
      }
#pragma unroll
      for (int r = 0; r < 4; ++r) {
        int row = rt * 16 + fg * 4 + r;
        B_lds[row * 136 + ncol0 + fc] = (short)f2bf(fmaxf(a0[r], 0.f));
        B_lds[row * 136 + ncol0 + 16 + fc] = (short)f2bf(fmaxf(a1[r], 0.f));
      }
    }
  }
  __syncthreads();

  // ---- node-MLP layer 2 + column-sum ----
  float acc0 = 0.f, acc1 = 0.f;
  {
    float b2v0 = nb2[ncol0 + fc], b2v1 = nb2[ncol0 + 16 + fc];
    bf16x8 BN2[2][4];
#pragma unroll
    for (int nt = 0; nt < 2; ++nt)
#pragma unroll
      for (int kt = 0; kt < 4; ++kt)
        BN2[nt][kt] = *(const bf16x8*)(nw2T + (ncol0 + nt * 16 + fc) * 128 + kt * 32 + fg * 8);
#pragma unroll
    for (int rt = 0; rt < 4; ++rt) {
      f32x4 a0 = {b2v0, b2v0, b2v0, b2v0};
      f32x4 a1 = {b2v1, b2v1, b2v1, b2v1};
#pragma unroll
      for (int kt = 0; kt < 4; ++kt) {
        bf16x8 hv = *(const bf16x8*)(&B_lds[(rt * 16 + fc) * 136 + kt * 32 + fg * 8]);
        a0 = mfma16(hv, BN2[0][kt], a0);
        a1 = mfma16(hv, BN2[1][kt], a1);
      }
#pragma unroll
      for (int r = 0; r < 4; ++r) {
        int node = n0 + rt * 16 + fg * 4 + r;
        if (node < NN) {
          acc0 += fmaxf(a0[r], 0.f);
          acc1 += fmaxf(a1[r], 0.f);
        }
      }
    }
  }
  acc0 += __shfl_xor(acc0, 16); acc0 += __shfl_xor(acc0, 32);
  acc1 += __shfl_xor(acc1, 16); acc1 += __shfl_xor(acc1, 32);
  if (fg == 0) {
    const int stripe = blockIdx.x & (STRIPES - 1);
    float* base = node_acc + ((size_t)b * STRIPES + stripe) * 128;
    atomicAdd(base + ncol0 + fc, acc0);
    atomicAdd(base + ncol0 + 16 + fc, acc1);
  }
}

// edge kernel v4: h1 = relu(Xs[src]+Xd[dst]+E@W1E+b1) with fp16 register gather
// (adds in f32); m = relu(h1@eW2+b2)*gate
__global__ __launch_bounds__(256, 4) void edge_kernel3(
    const unsigned short* __restrict__ Xs, const unsigned short* __restrict__ Xd,
    const float* __restrict__ E, const int* __restrict__ edges,
    const short* __restrict__ w1eT, const short* __restrict__ pwT,
    const short* __restrict__ ew2T, const float* __restrict__ eb1,
    const float* __restrict__ eb2, const float* __restrict__ gsp,
    float* __restrict__ edge_acc) {
  __shared__ __align__(16) short h1s[64 * 128];   // swizzled bf16, 16 KB
  __shared__ __align__(16) short E_lds[64 * 40];  // pitch 40 shorts, 5 KB
  __shared__ float gate_lds[64];
  __shared__ __align__(8) int idx_lds[128];

  const int tid = threadIdx.x;
  const int lane = tid & 63;
  const int w = tid >> 6;
  const int fc = lane & 15;
  const int fg = lane >> 4;
  const int ncol0 = w * 32;
  const int b = blockIdx.y;
  const float gs = gsp[0];
  const float* E_b = E + (size_t)b * ME * 16;
  const int* edges_b = edges + (size_t)b * ME * 2;
  const unsigned short* Xs_b = Xs + (size_t)b * NN * 128;
  const unsigned short* Xd_b = Xd + (size_t)b * NN * 128;
  const f32x4 zf = {0.f, 0.f, 0.f, 0.f};

  // persistent fragments (table-col space; eb1 in hidden space)
  bf16x8 W1E[2], PW[2], B2f[2][4];
  float eb1v[2], eb2v[2];
#pragma unroll
  for (int nt = 0; nt < 2; ++nt) {
    int col = ncol0 + nt * 16 + fc;
    W1E[nt] = *(const bf16x8*)(w1eT + col * 32 + fg * 8);
    PW[nt] = *(const bf16x8*)(pwT + col * 32 + fg * 8);
#pragma unroll
    for (int kt = 0; kt < 4; ++kt)
      B2f[nt][kt] = *(const bf16x8*)(ew2T + col * 128 + kt * 32 + fg * 8);
    eb1v[nt] = eb1[ncol0 + 2 * fc + nt];  // hid(col)
    eb2v[nt] = eb2[col];
  }

  // zero E_lds k=16..31 once (never rewritten)
  if (tid < 64) {
    uint4 z = {0, 0, 0, 0};
    *(uint4*)(&E_lds[tid * 40 + 16]) = z;
    *(uint4*)(&E_lds[tid * 40 + 24]) = z;
  }

  const int et = tid >> 2, eq = tid & 3;  // E staging: 4 threads/edge
  const int cb = ncol0 + 2 * fc;          // this thread's hidden col pair
  float accm0 = 0.f, accm1 = 0.f, accp0 = 0.f, accp1 = 0.f, accg = 0.f;

  for (int it = 0; it < NT2; ++it) {
    const int e0 = (blockIdx.x * NT2 + it) * 64;
    // ---- stage: idx, E (bf16 RNE), gate ----
    if (tid < 128) idx_lds[tid] = edges_b[(size_t)e0 * 2 + tid];
    {
      float4 fe = ((const float4*)E_b)[(size_t)(e0 + et) * 4 + eq];
      uint2 ue;
      ue.x = (unsigned)f2bf(fe.x) | ((unsigned)f2bf(fe.y) << 16);
      ue.y = (unsigned)f2bf(fe.z) | ((unsigned)f2bf(fe.w) << 16);
      *(uint2*)(&E_lds[et * 40 + eq * 4]) = ue;
      if (eq == 0) gate_lds[et] = fminf(fmaxf(1.f + gs * fe.z, 0.f), 3.f);
    }
    __syncthreads();

    // ---- phase 1: per-rt {prefetch rt+1 gathers; E-MFMA; combine f32; h1->LDS} ----
    unsigned gsv[2][4], gdv[2][4];
#define LOAD_RT(P, RT)                                                        \
    {                                                                         \
      _Pragma("unroll")                                                       \
      for (int r = 0; r < 4; ++r) {                                           \
        int row = (RT) * 16 + fg * 4 + r;                                     \
        int2 sd = *(const int2*)(&idx_lds[2 * row]);                          \
        gsv[P][r] = *(const unsigned*)(Xs_b + (size_t)sd.x * 128 + cb);       \
        gdv[P][r] = *(const unsigned*)(Xd_b + (size_t)sd.y * 128 + cb);       \
      }                                                                       \
    }
    LOAD_RT(0, 0)
#pragma unroll
    for (int rt = 0; rt < 4; ++rt) {
      if (rt < 3) LOAD_RT((rt + 1) & 1, rt + 1)
      bf16x8 Ef = *(const bf16x8*)(&E_lds[(rt * 16 + fc) * 40 + fg * 8]);
      f32x4 a0 = {eb1v[0], eb1v[0], eb1v[0], eb1v[0]};
      f32x4 a1 = {eb1v[1], eb1v[1], eb1v[1], eb1v[1]};
      a0 = mfma16(Ef, W1E[0], a0);
      a1 = mfma16(Ef, W1E[1], a1);
      f32x4 q0 = mfma16(Ef, PW[0], zf);
      f32x4 q1 = mfma16(Ef, PW[1], zf);
#pragma unroll
      for (int r = 0; r < 4; ++r) {
        int row = rt * 16 + fg * 4 + r;
        float g = gate_lds[row];
        accp0 += q0[r] * g;
        accp1 += q1[r] * g;
        float2 s = h2f2(gsv[rt & 1][r]);
        float2 d = h2f2(gdv[rt & 1][r]);
        float v0 = fmaxf(a0[r] + s.x + d.x, 0.f);
        float v1 = fmaxf(a1[r] + s.y + d.y, 0.f);
        int di = row * 64 + ((w * 16 + fc) ^ ((row & 7) << 2));
        ((unsigned*)h1s)[di] = (unsigned)f2bf(v0) | ((unsigned)f2bf(v1) << 16);
      }
    }
#undef LOAD_RT
    __syncthreads();

    // ---- phase 2: layer 2 (+bias via C-init) ----
    if (w == 0) accg += gate_lds[lane];
#pragma unroll
    for (int rt = 0; rt < 4; ++rt) {
      const int arow = rt * 16 + fc;
      f32x4 a0 = {eb2v[0], eb2v[0], eb2v[0], eb2v[0]};
      f32x4 a1 = {eb2v[1], eb2v[1], eb2v[1], eb2v[1]};
#pragma unroll
      for (int kt = 0; kt < 4; ++kt) {
        bf16x8 hv = *(const bf16x8*)(&h1s[arow * 128 + ((kt * 32 + fg * 8) ^ ((arow & 7) << 3))]);
        a0 = mfma16(hv, B2f[0][kt], a0);
        a1 = mfma16(hv, B2f[1][kt], a1);
      }
#pragma unroll
      for (int r = 0; r < 4; ++r) {
        int row = rt * 16 + fg * 4 + r;
        float g = gate_lds[row];
        accm0 += fmaxf(a0[r], 0.f) * g;
        accm1 += fmaxf(a1[r], 0.f) * g;
      }
    }
    __syncthreads();
  }

  // ---- reduce over fg, striped atomics ----
  accm0 += __shfl_xor(accm0, 16); accm0 += __shfl_xor(accm0, 32);
  accm1 += __shfl_xor(accm1, 16); accm1 += __shfl_xor(accm1, 32);
  accp0 += __shfl_xor(accp0, 16); accp0 += __shfl_xor(accp0, 32);
  accp1 += __shfl_xor(accp1, 16); accp1 += __shfl_xor(accp1, 32);
  const int stripe = blockIdx.x & (STRIPES - 1);
  float* base = edge_acc + ((size_t)b * STRIPES + stripe) * 264;
  if (fg == 0) {
    atomicAdd(base + ncol0 + fc, accm0);
    atomicAdd(base + ncol0 + 16 + fc, accm1);
    atomicAdd(base + 128 + ncol0 + fc, accp0);
    atomicAdd(base + 128 + ncol0 + 16 + fc, accp1);
  }
  if (w == 0) {
#pragma unroll
    for (int off = 1; off < 64; off <<= 1) accg += __shfl_xor(accg, off);
    if (lane == 0) atomicAdd(base + 256, accg);
  }
}

// ================= fallback path (round-3, known-good) =================

__global__ void prep_w_fb(const float* __restrict__ eW1, const float* __restrict__ eW2,
                          const float* __restrict__ nW1, const float* __restrict__ nW2,
                          const float* __restrict__ pW,
                          short* __restrict__ ew1T, short* __restrict__ ew2T,
                          short* __restrict__ nw1T, short* __restrict__ nw2T,
                          short* __restrict__ pwT) {
  int c = blockIdx.x;
  int t = threadIdx.x;
  for (int k = t; k < 288; k += 256)
    ew1T[c * 288 + k] = (k < 272) ? (short)f2bf(eW1[(size_t)k * 128 + c]) : (short)0;
  if (t < 128) {
    ew2T[c * 128 + t] = (short)f2bf(eW2[(size_t)t * 128 + c]);
    nw1T[c * 128 + t] = (short)f2bf(nW1[(size_t)t * 128 + c]);
    nw2T[c * 128 + t] = (short)f2bf(nW2[(size_t)t * 128 + c]);
  }
  if (t < 32) pwT[c * 32 + t] = (t < 16) ? (short)f2bf(pW[(size_t)t * 128 + c]) : (short)0;
}

template<bool WRITEBF>
__global__ __launch_bounds__(256, 2) void node_kernel_fb(
    const float* __restrict__ X, short* __restrict__ Xbf,
    const short* __restrict__ nw1T, const short* __restrict__ nw2T,
    const float* __restrict__ nb1, const float* __restrict__ nb2,
    float* __restrict__ node_acc) {
  __shared__ __align__(16) short A_lds[64 * 136];
  __shared__ __align__(16) short h1_lds[64 * 136];
  const int tid = threadIdx.x;
  const int lane = tid & 63;
  const int w = tid >> 6;
  const int fc = lane & 15;
  const int fg = lane >> 4;
  const int ncol0 = w * 32;
  const int b = blockIdx.y;
  const float* X_b = X + (size_t)b * NN * 128;
  short* Xbf_b = Xbf + (size_t)b * NN * 128;

  bf16x8 B1[2][4], B2[2][4];
  float b1v[2], b2v[2];
#pragma unroll
  for (int nt = 0; nt < 2; ++nt) {
    int col = ncol0 + nt * 16 + fc;
#pragma unroll
    for (int kt = 0; kt < 4; ++kt) {
      B1[nt][kt] = *reinterpret_cast<const bf16x8*>(nw1T + col * 128 + kt * 32 + fg * 8);
      B2[nt][kt] = *reinterpret_cast<const bf16x8*>(nw2T + col * 128 + kt * 32 + fg * 8);
    }
    b1v[nt] = nb1[col];
    b2v[nt] = nb2[col];
  }

  const int n0 = blockIdx.x * 64;
#pragma unroll
  for (int p = 0; p < 8; ++p) {
    int slot = p * 256 + tid;
    int row = slot >> 5, chunk = slot & 31;
    int node = n0 + row;
    ushort4 v = {0, 0, 0, 0};
    if (node < NN) {
      float4 f = *reinterpret_cast<const float4*>(X_b + (size_t)node * 128 + chunk * 4);
      v.x = f2bf(f.x); v.y = f2bf(f.y); v.z = f2bf(f.z); v.w = f2bf(f.w);
      if (WRITEBF) *reinterpret_cast<ushort4*>(Xbf_b + (size_t)node * 128 + chunk * 4) = v;
    }
    *reinterpret_cast<ushort4*>(&A_lds[row * 136 + chunk * 4]) = v;
  }
  __syncthreads();

  f32x4 zf = {0.f, 0.f, 0.f, 0.f};
  float acc0 = 0.f, acc1 = 0.f;
#pragma unroll
  for (int rt = 0; rt < 4; ++rt) {
    const short* arow = &A_lds[(rt * 16 + fc) * 136 + fg * 8];
    f32x4 a0 = zf, a1 = zf;
#pragma unroll
    for (int kt = 0; kt < 4; ++kt) {
      bf16x8 av = *reinterpret_cast<const bf16x8*>(arow + kt * 32);
      a0 = mfma16(av, B1[0][kt], a0);
      a1 = mfma16(av, B1[1][kt], a1);
    }
#pragma unroll
    for (int r = 0; r < 4; ++r) {
      int row = rt * 16 + fg * 4 + r;
      h1_lds[row * 136 + ncol0 + fc] = (short)f2bf(fmaxf(a0[r] + b1v[0], 0.f));
      h1_lds[row * 136 + ncol0 + 16 + fc] = (short)f2bf(fmaxf(a1[r] + b1v[1], 0.f));
    }
  }
  __syncthreads();
#pragma unroll
  for (int rt = 0; rt < 4; ++rt) {
    const short* hrow = &h1_lds[(rt * 16 + fc) * 136 + fg * 8];
    f32x4 a0 = zf, a1 = zf;
#pragma unroll
    for (int kt = 0; kt < 4; ++kt) {
      bf16x8 hv = *reinterpret_cast<const bf16x8*>(hrow + kt * 32);
      a0 = mfma16(hv, B2[0][kt], a0);
      a1 = mfma16(hv, B2[1][kt], a1);
    }
#pragma unroll
    for (int r = 0; r < 4; ++r) {
      int row = n0 + rt * 16 + fg * 4 + r;
      if (row < NN) {
        acc0 += fmaxf(a0[r] + b2v[0], 0.f);
        acc1 += fmaxf(a1[r] + b2v[1], 0.f);
      }
    }
  }
  acc0 += __shfl_xor(acc0, 16); acc0 += __shfl_xor(acc0, 32);
  acc1 += __shfl_xor(acc1, 16); acc1 += __shfl_xor(acc1, 32);
  if (fg == 0) {
    const int stripe = blockIdx.x & (STRIPES - 1);
    float* base = node_acc + ((size_t)b * STRIPES + stripe) * 128;
    atomicAdd(base + ncol0 + fc, acc0);
    atomicAdd(base + ncol0 + 16 + fc, acc1);
  }
}

template<bool XBF>
__global__ __launch_bounds__(256, 2) void edge_kernel_fb(
    const short* __restrict__ Xbf, const float* __restrict__ X,
    const float* __restrict__ E, const int* __restrict__ edges,
    const short* __restrict__ ew1T, const short* __restrict__ ew2T,
    const short* __restrict__ pwT, const float* __restrict__ eb1,
    const float* __restrict__ eb2, const float* __restrict__ gsp,
    float* __restrict__ edge_acc) {
  __shared__ __align__(16) short A_lds[64 * 296];
  __shared__ __align__(16) short h1_lds[64 * 136];
  __shared__ float gate_lds[2][64];
  __shared__ int idx_lds[2][128];

  const int tid = threadIdx.x;
  const int lane = tid & 63;
  const int w = tid >> 6;
  const int fc = lane & 15;
  const int fg = lane >> 4;
  const int ncol0 = w * 32;
  const int b = blockIdx.y;

  const float gs = gsp[0];
  const float* E_b = E + (size_t)b * ME * 16;
  const int* edges_b = edges + (size_t)b * ME * 2;
  const short* Xbf_b = Xbf + (size_t)b * NN * 128;
  const float* X_b = X + (size_t)b * NN * 128;
  const int tile0 = blockIdx.x * NT_FB;

  bf16x8 B1[2][9], B2[2][4], PWf[2];
  float eb1v[2], eb2v[2];
#pragma unroll
  for (int nt = 0; nt < 2; ++nt) {
    int col = ncol0 + nt * 16 + fc;
#pragma unroll
    for (int kt = 0; kt < 9; ++kt)
      B1[nt][kt] = *reinterpret_cast<const bf16x8*>(ew1T + col * 288 + kt * 32 + fg * 8);
#pragma unroll
    for (int kt = 0; kt < 4; ++kt)
      B2[nt][kt] = *reinterpret_cast<const bf16x8*>(ew2T + col * 128 + kt * 32 + fg * 8);
    PWf[nt] = *reinterpret_cast<const bf16x8*>(pwT + col * 32 + fg * 8);
    eb1v[nt] = eb1[col];
    eb2v[nt] = eb2[col];
  }

  const int grow = tid >> 1;
  const int ge = grow & 63;
  const int gsd = grow >> 6;
  const int gpos = (ge << 1) | gsd;
  const int ghalf = tid & 1;
  const int et = tid >> 2, q = tid & 3;

#define GATHER8(node, v0, v1, v2, v3, v4, v5, v6, v7)                                   \
  if (XBF) {                                                                            \
    const bf16x8* gp = reinterpret_cast<const bf16x8*>(Xbf_b + (size_t)(node)*128 + ghalf*64); \
    v0 = gp[0]; v1 = gp[1]; v2 = gp[2]; v3 = gp[3];                                     \
    v4 = gp[4]; v5 = gp[5]; v6 = gp[6]; v7 = gp[7];                                     \
  } else {                                                                              \
    const float4* gp = reinterpret_cast<const float4*>(X_b + (size_t)(node)*128 + ghalf*64); \
    v0 = pack2(gp[0], gp[1]);  v1 = pack2(gp[2], gp[3]);                                \
    v2 = pack2(gp[4], gp[5]);  v3 = pack2(gp[6], gp[7]);                                \
    v4 = pack2(gp[8], gp[9]);  v5 = pack2(gp[10], gp[11]);                              \
    v6 = pack2(gp[12], gp[13]); v7 = pack2(gp[14], gp[15]);                             \
  }

#define STORE8(v0, v1, v2, v3, v4, v5, v6, v7)                                          \
  {                                                                                     \
    bf16x8* aw8 = reinterpret_cast<bf16x8*>(&A_lds[ge * 296 + gsd * 128 + ghalf * 64]); \
    aw8[0] = v0; aw8[1] = v1; aw8[2] = v2; aw8[3] = v3;                                 \
    aw8[4] = v4; aw8[5] = v5; aw8[6] = v6; aw8[7] = v7;                                 \
  }

  if (tid < 64) {
    bf16x8 z = {0, 0, 0, 0, 0, 0, 0, 0};
    *reinterpret_cast<bf16x8*>(&A_lds[tid * 296 + 272]) = z;
    *reinterpret_cast<bf16x8*>(&A_lds[tid * 296 + 280]) = z;
  }
  {
    const int e0 = tile0 * 64;
    int node = edges_b[(size_t)e0 * 2 + gpos];
    bf16x8 s0, s1, s2, s3, s4, s5, s6, s7;
    GATHER8(node, s0, s1, s2, s3, s4, s5, s6, s7);
    STORE8(s0, s1, s2, s3, s4, s5, s6, s7);
    float4 ev = *reinterpret_cast<const float4*>(E_b + (size_t)e0 * 16 + tid * 4);
    ushort4 evb; evb.x = f2bf(ev.x); evb.y = f2bf(ev.y); evb.z = f2bf(ev.z); evb.w = f2bf(ev.w);
    *reinterpret_cast<ushort4*>(&A_lds[et * 296 + 256 + q * 4]) = evb;
    if (q == 0) gate_lds[0][et] = fminf(fmaxf(1.f + gs * ev.z, 0.f), 3.f);
    if (tid < 128) idx_lds[1][tid] = edges_b[(size_t)(tile0 + 1) * 64 * 2 + tid];
  }
  __syncthreads();

  float accm0 = 0.f, accm1 = 0.f, accp0 = 0.f, accp1 = 0.f, accg = 0.f;
  const f32x4 zf = {0.f, 0.f, 0.f, 0.f};

  for (int it = 0; it < NT_FB; ++it) {
    const int cur = it & 1, nxt = (it + 1) & 1;
    const bool hasn1 = (it + 1 < NT_FB);
    const bool hasn2 = (it + 2 < NT_FB);
    const int e0n = (hasn1 ? (tile0 + it + 1) : tile0) * 64;
    const int e0n2 = (hasn2 ? (tile0 + it + 2) : tile0) * 64;

    float4 epre = *reinterpret_cast<const float4*>(E_b + (size_t)e0n * 16 + tid * 4);
    int idxpre = 0;
    if (tid < 128) idxpre = edges_b[(size_t)e0n2 * 2 + tid];
    const int node = idx_lds[nxt][gpos];
    bf16x8 p0v, p1v, p2v, p3v, p4v, p5v, p6v, p7v;
    GATHER8(node, p0v, p1v, p2v, p3v, p4v, p5v, p6v, p7v);

#pragma unroll
    for (int rt = 0; rt < 4; ++rt) {
      const short* arow = &A_lds[(rt * 16 + fc) * 296 + fg * 8];
      f32x4 a0 = zf, a1 = zf;
#pragma unroll
      for (int kt = 0; kt < 9; ++kt) {
        bf16x8 av = *reinterpret_cast<const bf16x8*>(arow + kt * 32);
        a0 = mfma16(av, B1[0][kt], a0);
        a1 = mfma16(av, B1[1][kt], a1);
      }
      bf16x8 av8 = *reinterpret_cast<const bf16x8*>(arow + 256);
      f32x4 q0 = mfma16(av8, PWf[0], zf);
      f32x4 q1 = mfma16(av8, PWf[1], zf);
#pragma unroll
      for (int r = 0; r < 4; ++r) {
        int row = rt * 16 + fg * 4 + r;
        float g = gate_lds[cur][row];
        accp0 += q0[r] * g;
        accp1 += q1[r] * g;
        h1_lds[row * 136 + ncol0 + fc] = (short)f2bf(fmaxf(a0[r] + eb1v[0], 0.f));
        h1_lds[row * 136 + ncol0 + 16 + fc] = (short)f2bf(fmaxf(a1[r] + eb1v[1], 0.f));
      }
    }
    __syncthreads();

    if (hasn1) {
      STORE8(p0v, p1v, p2v, p3v, p4v, p5v, p6v, p7v);
      ushort4 evb; evb.x = f2bf(epre.x); evb.y = f2bf(epre.y); evb.z = f2bf(epre.z); evb.w = f2bf(epre.w);
      *reinterpret_cast<ushort4*>(&A_lds[et * 296 + 256 + q * 4]) = evb;
      if (q == 0) gate_lds[nxt][et] = fminf(fmaxf(1.f + gs * epre.z, 0.f), 3.f);
      if (tid < 128) idx_lds[cur][tid] = idxpre;
    }

    if (w == 0) accg += gate_lds[cur][lane];
#pragma unroll
    for (int rt = 0; rt < 4; ++rt) {
      const short* hrow = &h1_lds[(rt * 16 + fc) * 136 + fg * 8];
      f32x4 a0 = zf, a1 = zf;
#pragma unroll
      for (int kt = 0; kt < 4; ++kt) {
        bf16x8 hv = *reinterpret_cast<const bf16x8*>(hrow + kt * 32);
        a0 = mfma16(hv, B2[0][kt], a0);
        a1 = mfma16(hv, B2[1][kt], a1);
      }
#pragma unroll
      for (int r = 0; r < 4; ++r) {
        int row = rt * 16 + fg * 4 + r;
        float g = gate_lds[cur][row];
        accm0 += fmaxf(a0[r] + eb2v[0], 0.f) * g;
        accm1 += fmaxf(a1[r] + eb2v[1], 0.f) * g;
      }
    }
    __syncthreads();
  }

  accm0 += __shfl_xor(accm0, 16); accm0 += __shfl_xor(accm0, 32);
  accm1 += __shfl_xor(accm1, 16); accm1 += __shfl_xor(accm1, 32);
  accp0 += __shfl_xor(accp0, 16); accp0 += __shfl_xor(accp0, 32);
  accp1 += __shfl_xor(accp1, 16); accp1 += __shfl_xor(accp1, 32);
  const int stripe = blockIdx.x & (STRIPES - 1);
  float* base = edge_acc + ((size_t)b * STRIPES + stripe) * 264;
  if (fg == 0) {
    atomicAdd(base + ncol0 + fc, accm0);
    atomicAdd(base + ncol0 + 16 + fc, accm1);
    atomicAdd(base + 128 + ncol0 + fc, accp0);
    atomicAdd(base + 128 + ncol0 + 16 + fc, accp1);
  }
  if (w == 0) {
#pragma unroll
    for (int off = 1; off < 64; off <<= 1) accg += __shfl_xor(accg, off);
    if (lane == 0) atomicAdd(base + 256, accg);
  }
#undef GATHER8
#undef STORE8
}

// ---------------- final combine + readout head (exact f32, both paths) ----------------

__global__ void final_kernel(const float* __restrict__ edge_acc, const float* __restrict__ node_acc,
                             const float* __restrict__ pb, const float* __restrict__ rW1,
                             const float* __restrict__ rb1, const float* __restrict__ rW2,
                             const float* __restrict__ rb2, float* __restrict__ out) {
  int b = blockIdx.x;
  int j = threadIdx.x;  // 0..127
  __shared__ float feat[256];
  __shared__ float h[64];
  const float* ea = edge_acc + (size_t)b * STRIPES * 264;
  const float* na = node_acc + (size_t)b * STRIPES * 128;
  float ms = 0.f, ps = 0.f, hs = 0.f, gsum = 0.f;
  for (int s = 0; s < STRIPES; ++s) {
    ms += ea[s * 264 + j];
    ps += ea[s * 264 + 128 + j];
    hs += na[s * 128 + j];
    gsum += ea[s * 264 + 256];
  }
  feat[j] = (hs + 2.f * ms) * (1.f / (float)NN);
  feat[128 + j] = (ps + gsum * pb[j]) / ((float)ME + 1e-6f);
  __syncthreads();
  if (j < 64) {
    float a = rb1[j];
    for (int i = 0; i < 256; ++i) a += feat[i] * rW1[i * 64 + j];
    h[j] = fmaxf(a, 0.f);
  }
  __syncthreads();
  if (j < 2) {
    float a = rb2[j];
    for (int i = 0; i < 64; ++i) a += h[i] * rW2[i * 2 + j];
    out[b * 2 + j] = a;
  }
}

// ---------------- host ----------------

extern "C" void kernel_launch(void* const* d_in, const int* in_sizes, int n_in,
                              void* d_out, int out_size, void* d_ws, size_t ws_size,
                              hipStream_t stream) {
  const float* X = (const float*)d_in[0];
  const float* E = (const float*)d_in[1];
  const int* edges = (const int*)d_in[2];
  const float* nW1 = (const float*)d_in[3];
  const float* nb1 = (const float*)d_in[4];
  const float* nW2 = (const float*)d_in[5];
  const float* nb2 = (const float*)d_in[6];
  const float* eW1 = (const float*)d_in[7];
  const float* eb1 = (const float*)d_in[8];
  const float* eW2 = (const float*)d_in[9];
  const float* eb2 = (const float*)d_in[10];
  const float* pW = (const float*)d_in[11];
  const float* pb = (const float*)d_in[12];
  const float* rW1 = (const float*)d_in[13];
  const float* rb1 = (const float*)d_in[14];
  const float* rW2 = (const float*)d_in[15];
  const float* rb2 = (const float*)d_in[16];
  const float* gscale = (const float*)d_in[17];
  float* out = (float*)d_out;

  char* ws = (char*)d_ws;
  size_t off = 0;
  auto alloc = [&](size_t sz) -> void* {
    void* p = ws + off;
    off = (off + sz + 255) & ~(size_t)255;
    return p;
  };
  size_t acc_floats = (size_t)NB * STRIPES * 264 + (size_t)NB * STRIPES * 128;

  // ---- new-path layout (fp16 Xs/Xd) ----
  short* es1T = (short*)alloc(128 * 128 * 2);
  short* ed1T = (short*)alloc(128 * 128 * 2);
  short* w1eT = (short*)alloc(128 * 32 * 2);
  short* ew2T = (short*)alloc(128 * 128 * 2);
  short* nw1T = (short*)alloc(128 * 128 * 2);
  short* nw2T = (short*)alloc(128 * 128 * 2);
  short* pwT  = (short*)alloc(128 * 32 * 2);
  float* acc  = (float*)alloc(acc_floats * 4);
  unsigned short* Xs = (unsigned short*)alloc((size_t)NB * NN * 128 * 2);
  unsigned short* Xd = (unsigned short*)alloc((size_t)NB * NN * 128 * 2);
  bool fit = off <= ws_size;

  if (fit) {
    float* edge_acc = acc;
    float* node_acc = acc + (size_t)NB * STRIPES * 264;
    hipMemsetAsync(acc, 0, acc_floats * 4, stream);
    prep_w2<<<dim3(128), dim3(256), 0, stream>>>(eW1, eW2, nW1, nW2, pW,
                                                 es1T, ed1T, w1eT, ew2T, nw1T, nw2T, pwT);
    node_prep<<<dim3(313, 2), dim3(256), 0, stream>>>(X, nw1T, nw2T, es1T, ed1T,
                                                      nb1, nb2, Xs, Xd, node_acc);
    edge_kernel3<<<dim3(1000, 2), dim3(256), 0, stream>>>(Xs, Xd, E, edges, w1eT, pwT,
                                                          ew2T, eb1, eb2, gscale, edge_acc);
    final_kernel<<<dim3(NB), dim3(128), 0, stream>>>(edge_acc, node_acc, pb, rW1, rb1, rW2, rb2, out);
    return;
  }

  // ---- fallback: round-3 layout & kernels ----
  off = 0;
  short* ew1T_f = (short*)alloc(288 * 128 * 2);
  short* ew2T_f = (short*)alloc(128 * 128 * 2);
  short* nw1T_f = (short*)alloc(128 * 128 * 2);
  short* nw2T_f = (short*)alloc(128 * 128 * 2);
  short* pwT_f  = (short*)alloc(32 * 128 * 2);
  float* acc_f  = (float*)alloc(acc_floats * 4);
  float* edge_acc = acc_f;
  float* node_acc = acc_f + (size_t)NB * STRIPES * 264;
  size_t xbf_bytes = (size_t)NB * NN * 128 * 2;
  size_t off_before_xbf = off;
  short* Xbf = (short*)alloc(xbf_bytes);
  bool use_xbf = (off_before_xbf + xbf_bytes) <= ws_size;

  hipMemsetAsync(acc_f, 0, acc_floats * 4, stream);
  prep_w_fb<<<dim3(128), dim3(256), 0, stream>>>(eW1, eW2, nW1, nW2, pW,
                                                 ew1T_f, ew2T_f, nw1T_f, nw2T_f, pwT_f);
  if (use_xbf) {
    node_kernel_fb<true><<<dim3(313, 2), dim3(256), 0, stream>>>(X, Xbf, nw1T_f, nw2T_f, nb1, nb2, node_acc);
    edge_kernel_fb<true><<<dim3(625, 2), dim3(256), 0, stream>>>(
        Xbf, X, E, edges, ew1T_f, ew2T_f, pwT_f, eb1, eb2, gscale, edge_acc);
  } else {
    node_kernel_fb<false><<<dim3(313, 2), dim3(256), 0, stream>>>(X, Xbf, nw1T_f, nw2T_f, nb1, nb2, node_acc);
    edge_kernel_fb<false><<<dim3(625, 2), dim3(256), 0, stream>>>(
        Xbf, X, E, edges, ew1T_f, ew2T_f, pwT_f, eb1, eb2, gscale, edge_acc);
  }
  final_kernel<<<dim3(NB), dim3(128), 0, stream>>>(edge_acc, node_acc, pb, rW1, rb1, rW2, rb2, out);
}

// Round 8
// 325.932 us; speedup vs baseline: 1.2121x; 1.0267x over previous
//
#include <hip/hip_runtime.h>
#include <hip/hip_fp16.h>

typedef short bf16x8 __attribute__((ext_vector_type(8)));
typedef float f32x4 __attribute__((ext_vector_type(4)));

#define NB 2
#define NN 20000
#define ME 320000
#define STRIPES 64
#define NT_FB 8  // tiles per block, fallback edge kernel
#define NT2 5    // tiles per block, new edge kernel (5000 tiles / 1000 blocks)

__device__ __forceinline__ unsigned short f2bf(float f) {
  union { float f; unsigned int u; } v; v.f = f;
  unsigned int r = (v.u + 0x7FFFu + ((v.u >> 16) & 1u)) >> 16;  // RNE
  return (unsigned short)r;
}

__device__ __forceinline__ unsigned short f2h(float f) {
  return __half_as_ushort(__float2half_rn(f));  // fp16 RNE
}

__device__ __forceinline__ float2 h2f2(unsigned u) {
  union { unsigned u; __half2 h; } v; v.u = u;
  return make_float2(__low2float(v.h), __high2float(v.h));
}

__device__ __forceinline__ bf16x8 pack2(float4 a, float4 b) {
  bf16x8 v;
  v[0]=(short)f2bf(a.x); v[1]=(short)f2bf(a.y); v[2]=(short)f2bf(a.z); v[3]=(short)f2bf(a.w);
  v[4]=(short)f2bf(b.x); v[5]=(short)f2bf(b.y); v[6]=(short)f2bf(b.z); v[7]=(short)f2bf(b.w);
  return v;
}

__device__ __forceinline__ f32x4 mfma16(bf16x8 a, bf16x8 b, f32x4 c) {
  return __builtin_amdgcn_mfma_f32_16x16x32_bf16(a, b, c, 0, 0, 0);
}

// hidden-col interleave: table col c holds hidden column hid(c) = (c&~31) + 2*(c&15) + ((c>>4)&1),
// so a wave's frag pair (nt=0,nt=1) at lane fc covers adjacent hidden cols (2fc, 2fc+1).
__device__ __forceinline__ int hidcol(int c) {
  return (c & ~31) + 2 * (c & 15) + ((c >> 4) & 1);
}

// ================= new path =================

__global__ void prep_w2(const float* __restrict__ eW1, const float* __restrict__ eW2,
                        const float* __restrict__ nW1, const float* __restrict__ nW2,
                        const float* __restrict__ pW,
                        short* __restrict__ es1T, short* __restrict__ ed1T,
                        short* __restrict__ w1eT, short* __restrict__ ew2T,
                        short* __restrict__ nw1T, short* __restrict__ nw2T,
                        short* __restrict__ pwT,
                        float* __restrict__ acc, int acc_n) {
  int c = blockIdx.x;   // 0..127 table column
  int t = threadIdx.x;  // 256
  int hc = hidcol(c);
  // zero the accumulator buffers (replaces hipMemsetAsync launch)
  for (int i = c * 256 + t; i < acc_n; i += 128 * 256) acc[i] = 0.f;
  if (t < 128) {
    es1T[c * 128 + t] = (short)f2bf(eW1[(size_t)t * 128 + hc]);
    ed1T[c * 128 + t] = (short)f2bf(eW1[(size_t)(128 + t) * 128 + hc]);
    ew2T[c * 128 + t] = (short)f2bf(eW2[(size_t)t * 128 + c]);
    nw1T[c * 128 + t] = (short)f2bf(nW1[(size_t)t * 128 + c]);
    nw2T[c * 128 + t] = (short)f2bf(nW2[(size_t)t * 128 + c]);
  }
  if (t < 32) {
    w1eT[c * 32 + t] = (t < 16) ? (short)f2bf(eW1[(size_t)(256 + t) * 128 + hc]) : (short)0;
    pwT[c * 32 + t]  = (t < 16) ? (short)f2bf(pW[(size_t)t * 128 + c]) : (short)0;
  }
}

// node_prep: per 64-node tile, stage X once; emit fp16 Xs = X@eW1[0:128] (hidden-linear
// cols), fp16 Xd = X@eW1[128:256], and the node-MLP Hx column-sums.
__global__ __launch_bounds__(256, 4) void node_prep(
    const float* __restrict__ X,
    const short* __restrict__ nw1T, const short* __restrict__ nw2T,
    const short* __restrict__ es1T, const short* __restrict__ ed1T,
    const float* __restrict__ nb1, const float* __restrict__ nb2,
    unsigned short* __restrict__ Xs, unsigned short* __restrict__ Xd,
    float* __restrict__ node_acc) {
  __shared__ __align__(16) short A_lds[64 * 136];
  __shared__ __align__(16) short B_lds[64 * 136];
  const int tid = threadIdx.x;
  const int lane = tid & 63;
  const int w = tid >> 6;
  const int fc = lane & 15;
  const int fg = lane >> 4;
  const int ncol0 = w * 32;
  const int b = blockIdx.y;
  const int n0 = blockIdx.x * 64;
  const float* X_b = X + (size_t)b * NN * 128;
  unsigned short* Xs_b = Xs + (size_t)b * NN * 128;
  unsigned short* Xd_b = Xd + (size_t)b * NN * 128;
  const f32x4 zf = {0.f, 0.f, 0.f, 0.f};

  // stage X tile (bf16, RNE)
#pragma unroll
  for (int p = 0; p < 8; ++p) {
    int slot = p * 256 + tid;
    int row = slot >> 5, chunk = slot & 31;
    int node = n0 + row;
    uint2 v = {0, 0};
    if (node < NN) {
      float4 f = *(const float4*)(X_b + (size_t)node * 128 + chunk * 4);
      v.x = (unsigned)f2bf(f.x) | ((unsigned)f2bf(f.y) << 16);
      v.y = (unsigned)f2bf(f.z) | ((unsigned)f2bf(f.w) << 16);
    }
    *(uint2*)(&A_lds[row * 136 + chunk * 4]) = v;
  }
  __syncthreads();

  // ---- GEMM-S -> direct fp16 store (hidden-linear: cols ncol0+2fc, +1) ----
  {
    bf16x8 BS[2][4];
#pragma unroll
    for (int nt = 0; nt < 2; ++nt)
#pragma unroll
      for (int kt = 0; kt < 4; ++kt)
        BS[nt][kt] = *(const bf16x8*)(es1T + (ncol0 + nt * 16 + fc) * 128 + kt * 32 + fg * 8);
#pragma unroll
    for (int rt = 0; rt < 4; ++rt) {
      f32x4 a0 = zf, a1 = zf;
#pragma unroll
      for (int kt = 0; kt < 4; ++kt) {
        bf16x8 av = *(const bf16x8*)(&A_lds[(rt * 16 + fc) * 136 + kt * 32 + fg * 8]);
        a0 = mfma16(av, BS[0][kt], a0);
        a1 = mfma16(av, BS[1][kt], a1);
      }
#pragma unroll
      for (int r = 0; r < 4; ++r) {
        int node = n0 + rt * 16 + fg * 4 + r;
        if (node < NN) {
          unsigned o = (unsigned)f2h(a0[r]) | ((unsigned)f2h(a1[r]) << 16);
          *(unsigned*)(Xs_b + (size_t)node * 128 + ncol0 + 2 * fc) = o;
        }
      }
    }
  }
  // ---- GEMM-D -> direct fp16 store ----
  {
    bf16x8 BD[2][4];
#pragma unroll
    for (int nt = 0; nt < 2; ++nt)
#pragma unroll
      for (int kt = 0; kt < 4; ++kt)
        BD[nt][kt] = *(const bf16x8*)(ed1T + (ncol0 + nt * 16 + fc) * 128 + kt * 32 + fg * 8);
#pragma unroll
    for (int rt = 0; rt < 4; ++rt) {
      f32x4 a0 = zf, a1 = zf;
#pragma unroll
      for (int kt = 0; kt < 4; ++kt) {
        bf16x8 av = *(const bf16x8*)(&A_lds[(rt * 16 + fc) * 136 + kt * 32 + fg * 8]);
        a0 = mfma16(av, BD[0][kt], a0);
        a1 = mfma16(av, BD[1][kt], a1);
      }
#pragma unroll
      for (int r = 0; r < 4; ++r) {
        int node = n0 + rt * 16 + fg * 4 + r;
        if (node < NN) {
          unsigned o = (unsigned)f2h(a0[r]) | ((unsigned)f2h(a1[r]) << 16);
          *(unsigned*)(Xd_b + (size_t)node * 128 + ncol0 + 2 * fc) = o;
        }
      }
    }
  }
  // ---- node-MLP layer 1 -> B_lds (plain cols, bias via C-init, relu, RNE) ----
  {
    float b1v0 = nb1[ncol0 + fc], b1v1 = nb1[ncol0 + 16 + fc];
    bf16x8 BN[2][4];
#pragma unroll
    for (int nt = 0; nt < 2; ++nt)
#pragma unroll
      for (int kt = 0; kt < 4; ++kt)
        BN[nt][kt] = *(const bf16x8*)(nw1T + (ncol0 + nt * 16 + fc) * 128 + kt * 32 + fg * 8);
#pragma unroll
    for (int rt = 0; rt < 4; ++rt) {
      f32x4 a0 = {b1v0, b1v0, b1v0, b1v0};
      f32x4 a1 = {b1v1, b1v1, b1v1, b1v1};
#pragma unroll
      for (int kt = 0; kt < 4; ++kt) {
        bf16x8 av = *(const bf16x8*)(&A_lds[(rt * 16 + fc) * 136 + kt * 32 + fg * 8]);
        a0 = mfma16(av, BN[0][kt], a0);
        a1 = mfma16(av, BN[1][kt], a1);
      }
#pragma unroll
      for (int r = 0; r < 4; ++r) {
        int row = rt * 16 + fg * 4 + r;
        B_lds[row * 136 + ncol0 + fc] = (short)f2bf(fmaxf(a0[r], 0.f));
        B_lds[row * 136 + ncol0 + 16 + fc] = (short)f2bf(fmaxf(a1[r], 0.f));
      }
    }
  }
  __syncthreads();

  // ---- node-MLP layer 2 + column-sum ----
  float acc0 = 0.f, acc1 = 0.f;
  {
    float b2v0 = nb2[ncol0 + fc], b2v1 = nb2[ncol0 + 16 + fc];
    bf16x8 BN2[2][4];
#pragma unroll
    for (int nt = 0; nt < 2; ++nt)
#pragma unroll
      for (int kt = 0; kt < 4; ++kt)
        BN2[nt][kt] = *(const bf16x8*)(nw2T + (ncol0 + nt * 16 + fc) * 128 + kt * 32 + fg * 8);
#pragma unroll
    for (int rt = 0; rt < 4; ++rt) {
      f32x4 a0 = {b2v0, b2v0, b2v0, b2v0};
      f32x4 a1 = {b2v1, b2v1, b2v1, b2v1};
#pragma unroll
      for (int kt = 0; kt < 4; ++kt) {
        bf16x8 hv = *(const bf16x8*)(&B_lds[(rt * 16 + fc) * 136 + kt * 32 + fg * 8]);
        a0 = mfma16(hv, BN2[0][kt], a0);
        a1 = mfma16(hv, BN2[1][kt], a1);
      }
#pragma unroll
      for (int r = 0; r < 4; ++r) {
        int node = n0 + rt * 16 + fg * 4 + r;
        if (node < NN) {
          acc0 += fmaxf(a0[r], 0.f);
          acc1 += fmaxf(a1[r], 0.f);
        }
      }
    }
  }
  acc0 += __shfl_xor(acc0, 16); acc0 += __shfl_xor(acc0, 32);
  acc1 += __shfl_xor(acc1, 16); acc1 += __shfl_xor(acc1, 32);
  if (fg == 0) {
    const int stripe = blockIdx.x & (STRIPES - 1);
    float* base = node_acc + ((size_t)b * STRIPES + stripe) * 128;
    atomicAdd(base + ncol0 + fc, acc0);
    atomicAdd(base + ncol0 + 16 + fc, acc1);
  }
}

// edge kernel v5: coalesced LDS-staged gather. Gather phase: wave w owns rows
// [16w,16w+16); lane l reads the fp16 pair at col 2l of Xs[src]/Xd[dst] (one
// 256B-contiguous wave transaction per row per side), sums in f32, stores fp16
// sum to swizzled Gsum. Phase 1 reads its 4B from LDS.
__global__ __launch_bounds__(256, 4) void edge_kernel5(
    const unsigned short* __restrict__ Xs, const unsigned short* __restrict__ Xd,
    const float* __restrict__ E, const int* __restrict__ edges,
    const short* __restrict__ w1eT, const short* __restrict__ pwT,
    const short* __restrict__ ew2T, const float* __restrict__ eb1,
    const float* __restrict__ eb2, const float* __restrict__ gsp,
    float* __restrict__ edge_acc) {
  __shared__ __align__(16) short h1s[64 * 128];   // swizzled bf16, 16 KB
  __shared__ __align__(16) short Gsum[64 * 128];  // swizzled fp16 sums, 16 KB
  __shared__ __align__(16) short E_lds[64 * 40];  // pitch 40 shorts, 5 KB
  __shared__ float gate_lds[64];
  __shared__ __align__(8) int idx_lds[2][128];

  const int tid = threadIdx.x;
  const int lane = tid & 63;
  const int w = tid >> 6;
  const int fc = lane & 15;
  const int fg = lane >> 4;
  const int ncol0 = w * 32;
  const int b = blockIdx.y;
  const float gs = gsp[0];
  const float* E_b = E + (size_t)b * ME * 16;
  const int* edges_b = edges + (size_t)b * ME * 2;
  const unsigned short* Xs_b = Xs + (size_t)b * NN * 128;
  const unsigned short* Xd_b = Xd + (size_t)b * NN * 128;
  const f32x4 zf = {0.f, 0.f, 0.f, 0.f};
  unsigned* const Gw = (unsigned*)Gsum;

  // persistent fragments (table-col space; eb1 in hidden space)
  bf16x8 W1E[2], PW[2], B2f[2][4];
  float eb1v[2], eb2v[2];
#pragma unroll
  for (int nt = 0; nt < 2; ++nt) {
    int col = ncol0 + nt * 16 + fc;
    W1E[nt] = *(const bf16x8*)(w1eT + col * 32 + fg * 8);
    PW[nt] = *(const bf16x8*)(pwT + col * 32 + fg * 8);
#pragma unroll
    for (int kt = 0; kt < 4; ++kt)
      B2f[nt][kt] = *(const bf16x8*)(ew2T + col * 128 + kt * 32 + fg * 8);
    eb1v[nt] = eb1[ncol0 + 2 * fc + nt];  // hid(col)
    eb2v[nt] = eb2[col];
  }

  // zero E_lds k=16..31 once (never rewritten)
  if (tid < 64) {
    uint4 z = {0, 0, 0, 0};
    *(uint4*)(&E_lds[tid * 40 + 16]) = z;
    *(uint4*)(&E_lds[tid * 40 + 24]) = z;
  }

  const int et = tid >> 2, eq = tid & 3;  // E staging: 4 threads/edge
  float accm0 = 0.f, accm1 = 0.f, accp0 = 0.f, accp1 = 0.f, accg = 0.f;

  // prologue: idx for tile 0
  if (tid < 128) idx_lds[0][tid] = edges_b[(size_t)(blockIdx.x * NT2) * 128 + tid];
  __syncthreads();

  for (int it = 0; it < NT2; ++it) {
    const int cur = it & 1, nxt = cur ^ 1;
    const int e0 = (blockIdx.x * NT2 + it) * 64;

    // ---- gather phase: idx(t+1) prefetch; E+gate; Gsum = Xs[src]+Xd[dst] ----
    if (it + 1 < NT2 && tid < 128)
      idx_lds[nxt][tid] = edges_b[(size_t)(e0 + 64) * 2 + tid];
    {
      float4 fe = ((const float4*)E_b)[(size_t)(e0 + et) * 4 + eq];
      uint2 ue;
      ue.x = (unsigned)f2bf(fe.x) | ((unsigned)f2bf(fe.y) << 16);
      ue.y = (unsigned)f2bf(fe.z) | ((unsigned)f2bf(fe.w) << 16);
      *(uint2*)(&E_lds[et * 40 + eq * 4]) = ue;
      if (eq == 0) gate_lds[et] = fminf(fmaxf(1.f + gs * fe.z, 0.f), 3.f);
    }
    {
      unsigned au[16], ad[16];
#pragma unroll
      for (int rr = 0; rr < 16; ++rr) {
        int row = w * 16 + rr;
        int2 sd = *(const int2*)(&idx_lds[cur][2 * row]);
        au[rr] = *(const unsigned*)(Xs_b + (size_t)sd.x * 128 + 2 * lane);
        ad[rr] = *(const unsigned*)(Xd_b + (size_t)sd.y * 128 + 2 * lane);
      }
#pragma unroll
      for (int rr = 0; rr < 16; ++rr) {
        int row = w * 16 + rr;
        float2 fs = h2f2(au[rr]), fd = h2f2(ad[rr]);
        unsigned o = (unsigned)f2h(fs.x + fd.x) | ((unsigned)f2h(fs.y + fd.y) << 16);
        Gw[row * 64 + (lane ^ ((row & 7) << 2))] = o;
      }
    }
    __syncthreads();

    // ---- phase 1: E-part MFMA (+bias via C-init) + pW; h1 = relu(E@W1E + Gsum + b1) ----
#pragma unroll
    for (int rt = 0; rt < 4; ++rt) {
      bf16x8 Ef = *(const bf16x8*)(&E_lds[(rt * 16 + fc) * 40 + fg * 8]);
      f32x4 a0 = {eb1v[0], eb1v[0], eb1v[0], eb1v[0]};
      f32x4 a1 = {eb1v[1], eb1v[1], eb1v[1], eb1v[1]};
      a0 = mfma16(Ef, W1E[0], a0);
      a1 = mfma16(Ef, W1E[1], a1);
      f32x4 q0 = mfma16(Ef, PW[0], zf);
      f32x4 q1 = mfma16(Ef, PW[1], zf);
#pragma unroll
      for (int r = 0; r < 4; ++r) {
        int row = rt * 16 + fg * 4 + r;
        float g = gate_lds[row];
        accp0 += q0[r] * g;
        accp1 += q1[r] * g;
        float2 s = h2f2(Gw[row * 64 + ((16 * w + fc) ^ ((row & 7) << 2))]);
        float v0 = fmaxf(a0[r] + s.x, 0.f);
        float v1 = fmaxf(a1[r] + s.y, 0.f);
        int di = row * 64 + ((w * 16 + fc) ^ ((row & 7) << 2));
        ((unsigned*)h1s)[di] = (unsigned)f2bf(v0) | ((unsigned)f2bf(v1) << 16);
      }
    }
    __syncthreads();

    // ---- phase 2: layer 2 (+bias via C-init) ----
    if (w == 0) accg += gate_lds[lane];
#pragma unroll
    for (int rt = 0; rt < 4; ++rt) {
      const int arow = rt * 16 + fc;
      f32x4 a0 = {eb2v[0], eb2v[0], eb2v[0], eb2v[0]};
      f32x4 a1 = {eb2v[1], eb2v[1], eb2v[1], eb2v[1]};
#pragma unroll
      for (int kt = 0; kt < 4; ++kt) {
        bf16x8 hv = *(const bf16x8*)(&h1s[arow * 128 + ((kt * 32 + fg * 8) ^ ((arow & 7) << 3))]);
        a0 = mfma16(hv, B2f[0][kt], a0);
        a1 = mfma16(hv, B2f[1][kt], a1);
      }
#pragma unroll
      for (int r = 0; r < 4; ++r) {
        int row = rt * 16 + fg * 4 + r;
        float g = gate_lds[row];
        accm0 += fmaxf(a0[r], 0.f) * g;
        accm1 += fmaxf(a1[r], 0.f) * g;
      }
    }
    __syncthreads();
  }

  // ---- reduce over fg, striped atomics ----
  accm0 += __shfl_xor(accm0, 16); accm0 += __shfl_xor(accm0, 32);
  accm1 += __shfl_xor(accm1, 16); accm1 += __shfl_xor(accm1, 32);
  accp0 += __shfl_xor(accp0, 16); accp0 += __shfl_xor(accp0, 32);
  accp1 += __shfl_xor(accp1, 16); accp1 += __shfl_xor(accp1, 32);
  const int stripe = blockIdx.x & (STRIPES - 1);
  float* base = edge_acc + ((size_t)b * STRIPES + stripe) * 264;
  if (fg == 0) {
    atomicAdd(base + ncol0 + fc, accm0);
    atomicAdd(base + ncol0 + 16 + fc, accm1);
    atomicAdd(base + 128 + ncol0 + fc, accp0);
    atomicAdd(base + 128 + ncol0 + 16 + fc, accp1);
  }
  if (w == 0) {
#pragma unroll
    for (int off = 1; off < 64; off <<= 1) accg += __shfl_xor(accg, off);
    if (lane == 0) atomicAdd(base + 256, accg);
  }
}

// ================= fallback path (round-3, known-good) =================

__global__ void prep_w_fb(const float* __restrict__ eW1, const float* __restrict__ eW2,
                          const float* __restrict__ nW1, const float* __restrict__ nW2,
                          const float* __restrict__ pW,
                          short* __restrict__ ew1T, short* __restrict__ ew2T,
                          short* __restrict__ nw1T, short* __restrict__ nw2T,
                          short* __restrict__ pwT) {
  int c = blockIdx.x;
  int t = threadIdx.x;
  for (int k = t; k < 288; k += 256)
    ew1T[c * 288 + k] = (k < 272) ? (short)f2bf(eW1[(size_t)k * 128 + c]) : (short)0;
  if (t < 128) {
    ew2T[c * 128 + t] = (short)f2bf(eW2[(size_t)t * 128 + c]);
    nw1T[c * 128 + t] = (short)f2bf(nW1[(size_t)t * 128 + c]);
    nw2T[c * 128 + t] = (short)f2bf(nW2[(size_t)t * 128 + c]);
  }
  if (t < 32) pwT[c * 32 + t] = (t < 16) ? (short)f2bf(pW[(size_t)t * 128 + c]) : (short)0;
}

template<bool WRITEBF>
__global__ __launch_bounds__(256, 2) void node_kernel_fb(
    const float* __restrict__ X, short* __restrict__ Xbf,
    const short* __restrict__ nw1T, const short* __restrict__ nw2T,
    const float* __restrict__ nb1, const float* __restrict__ nb2,
    float* __restrict__ node_acc) {
  __shared__ __align__(16) short A_lds[64 * 136];
  __shared__ __align__(16) short h1_lds[64 * 136];
  const int tid = threadIdx.x;
  const int lane = tid & 63;
  const int w = tid >> 6;
  const int fc = lane & 15;
  const int fg = lane >> 4;
  const int ncol0 = w * 32;
  const int b = blockIdx.y;
  const float* X_b = X + (size_t)b * NN * 128;
  short* Xbf_b = Xbf + (size_t)b * NN * 128;

  bf16x8 B1[2][4], B2[2][4];
  float b1v[2], b2v[2];
#pragma unroll
  for (int nt = 0; nt < 2; ++nt) {
    int col = ncol0 + nt * 16 + fc;
#pragma unroll
    for (int kt = 0; kt < 4; ++kt) {
      B1[nt][kt] = *reinterpret_cast<const bf16x8*>(nw1T + col * 128 + kt * 32 + fg * 8);
      B2[nt][kt] = *reinterpret_cast<const bf16x8*>(nw2T + col * 128 + kt * 32 + fg * 8);
    }
    b1v[nt] = nb1[col];
    b2v[nt] = nb2[col];
  }

  const int n0 = blockIdx.x * 64;
#pragma unroll
  for (int p = 0; p < 8; ++p) {
    int slot = p * 256 + tid;
    int row = slot >> 5, chunk = slot & 31;
    int node = n0 + row;
    ushort4 v = {0, 0, 0, 0};
    if (node < NN) {
      float4 f = *reinterpret_cast<const float4*>(X_b + (size_t)node * 128 + chunk * 4);
      v.x = f2bf(f.x); v.y = f2bf(f.y); v.z = f2bf(f.z); v.w = f2bf(f.w);
      if (WRITEBF) *reinterpret_cast<ushort4*>(Xbf_b + (size_t)node * 128 + chunk * 4) = v;
    }
    *reinterpret_cast<ushort4*>(&A_lds[row * 136 + chunk * 4]) = v;
  }
  __syncthreads();

  f32x4 zf = {0.f, 0.f, 0.f, 0.f};
  float acc0 = 0.f, acc1 = 0.f;
#pragma unroll
  for (int rt = 0; rt < 4; ++rt) {
    const short* arow = &A_lds[(rt * 16 + fc) * 136 + fg * 8];
    f32x4 a0 = zf, a1 = zf;
#pragma unroll
    for (int kt = 0; kt < 4; ++kt) {
      bf16x8 av = *reinterpret_cast<const bf16x8*>(arow + kt * 32);
      a0 = mfma16(av, B1[0][kt], a0);
      a1 = mfma16(av, B1[1][kt], a1);
    }
#pragma unroll
    for (int r = 0; r < 4; ++r) {
      int row = rt * 16 + fg * 4 + r;
      h1_lds[row * 136 + ncol0 + fc] = (short)f2bf(fmaxf(a0[r] + b1v[0], 0.f));
      h1_lds[row * 136 + ncol0 + 16 + fc] = (short)f2bf(fmaxf(a1[r] + b1v[1], 0.f));
    }
  }
  __syncthreads();
#pragma unroll
  for (int rt = 0; rt < 4; ++rt) {
    const short* hrow = &h1_lds[(rt * 16 + fc) * 136 + fg * 8];
    f32x4 a0 = zf, a1 = zf;
#pragma unroll
    for (int kt = 0; kt < 4; ++kt) {
      bf16x8 hv = *reinterpret_cast<const bf16x8*>(hrow + kt * 32);
      a0 = mfma16(hv, B2[0][kt], a0);
      a1 = mfma16(hv, B2[1][kt], a1);
    }
#pragma unroll
    for (int r = 0; r < 4; ++r) {
      int row = n0 + rt * 16 + fg * 4 + r;
      if (row < NN) {
        acc0 += fmaxf(a0[r] + b2v[0], 0.f);
        acc1 += fmaxf(a1[r] + b2v[1], 0.f);
      }
    }
  }
  acc0 += __shfl_xor(acc0, 16); acc0 += __shfl_xor(acc0, 32);
  acc1 += __shfl_xor(acc1, 16); acc1 += __shfl_xor(acc1, 32);
  if (fg == 0) {
    const int stripe = blockIdx.x & (STRIPES - 1);
    float* base = node_acc + ((size_t)b * STRIPES + stripe) * 128;
    atomicAdd(base + ncol0 + fc, acc0);
    atomicAdd(base + ncol0 + 16 + fc, acc1);
  }
}

template<bool XBF>
__global__ __launch_bounds__(256, 2) void edge_kernel_fb(
    const short* __restrict__ Xbf, const float* __restrict__ X,
    const float* __restrict__ E, const int* __restrict__ edges,
    const short* __restrict__ ew1T, const short* __restrict__ ew2T,
    const short* __restrict__ pwT, const float* __restrict__ eb1,
    const float* __restrict__ eb2, const float* __restrict__ gsp,
    float* __restrict__ edge_acc) {
  __shared__ __align__(16) short A_lds[64 * 296];
  __shared__ __align__(16) short h1_lds[64 * 136];
  __shared__ float gate_lds[2][64];
  __shared__ int idx_lds[2][128];

  const int tid = threadIdx.x;
  const int lane = tid & 63;
  const int w = tid >> 6;
  const int fc = lane & 15;
  const int fg = lane >> 4;
  const int ncol0 = w * 32;
  const int b = blockIdx.y;

  const float gs = gsp[0];
  const float* E_b = E + (size_t)b * ME * 16;
  const int* edges_b = edges + (size_t)b * ME * 2;
  const short* Xbf_b = Xbf + (size_t)b * NN * 128;
  const float* X_b = X + (size_t)b * NN * 128;
  const int tile0 = blockIdx.x * NT_FB;

  bf16x8 B1[2][9], B2[2][4], PWf[2];
  float eb1v[2], eb2v[2];
#pragma unroll
  for (int nt = 0; nt < 2; ++nt) {
    int col = ncol0 + nt * 16 + fc;
#pragma unroll
    for (int kt = 0; kt < 9; ++kt)
      B1[nt][kt] = *reinterpret_cast<const bf16x8*>(ew1T + col * 288 + kt * 32 + fg * 8);
#pragma unroll
    for (int kt = 0; kt < 4; ++kt)
      B2[nt][kt] = *reinterpret_cast<const bf16x8*>(ew2T + col * 128 + kt * 32 + fg * 8);
    PWf[nt] = *reinterpret_cast<const bf16x8*>(pwT + col * 32 + fg * 8);
    eb1v[nt] = eb1[col];
    eb2v[nt] = eb2[col];
  }

  const int grow = tid >> 1;
  const int ge = grow & 63;
  const int gsd = grow >> 6;
  const int gpos = (ge << 1) | gsd;
  const int ghalf = tid & 1;
  const int et = tid >> 2, q = tid & 3;

#define GATHER8(node, v0, v1, v2, v3, v4, v5, v6, v7)                                   \
  if (XBF) {                                                                            \
    const bf16x8* gp = reinterpret_cast<const bf16x8*>(Xbf_b + (size_t)(node)*128 + ghalf*64); \
    v0 = gp[0]; v1 = gp[1]; v2 = gp[2]; v3 = gp[3];                                     \
    v4 = gp[4]; v5 = gp[5]; v6 = gp[6]; v7 = gp[7];                                     \
  } else {                                                                              \
    const float4* gp = reinterpret_cast<const float4*>(X_b + (size_t)(node)*128 + ghalf*64); \
    v0 = pack2(gp[0], gp[1]);  v1 = pack2(gp[2], gp[3]);                                \
    v2 = pack2(gp[4], gp[5]);  v3 = pack2(gp[6], gp[7]);                                \
    v4 = pack2(gp[8], gp[9]);  v5 = pack2(gp[10], gp[11]);                              \
    v6 = pack2(gp[12], gp[13]); v7 = pack2(gp[14], gp[15]);                             \
  }

#define STORE8(v0, v1, v2, v3, v4, v5, v6, v7)                                          \
  {                                                                                     \
    bf16x8* aw8 = reinterpret_cast<bf16x8*>(&A_lds[ge * 296 + gsd * 128 + ghalf * 64]); \
    aw8[0] = v0; aw8[1] = v1; aw8[2] = v2; aw8[3] = v3;                                 \
    aw8[4] = v4; aw8[5] = v5; aw8[6] = v6; aw8[7] = v7;                                 \
  }

  if (tid < 64) {
    bf16x8 z = {0, 0, 0, 0, 0, 0, 0, 0};
    *reinterpret_cast<bf16x8*>(&A_lds[tid * 296 + 272]) = z;
    *reinterpret_cast<bf16x8*>(&A_lds[tid * 296 + 280]) = z;
  }
  {
    const int e0 = tile0 * 64;
    int node = edges_b[(size_t)e0 * 2 + gpos];
    bf16x8 s0, s1, s2, s3, s4, s5, s6, s7;
    GATHER8(node, s0, s1, s2, s3, s4, s5, s6, s7);
    STORE8(s0, s1, s2, s3, s4, s5, s6, s7);
    float4 ev = *reinterpret_cast<const float4*>(E_b + (size_t)e0 * 16 + tid * 4);
    ushort4 evb; evb.x = f2bf(ev.x); evb.y = f2bf(ev.y); evb.z = f2bf(ev.z); evb.w = f2bf(ev.w);
    *reinterpret_cast<ushort4*>(&A_lds[et * 296 + 256 + q * 4]) = evb;
    if (q == 0) gate_lds[0][et] = fminf(fmaxf(1.f + gs * ev.z, 0.f), 3.f);
    if (tid < 128) idx_lds[1][tid] = edges_b[(size_t)(tile0 + 1) * 64 * 2 + tid];
  }
  __syncthreads();

  float accm0 = 0.f, accm1 = 0.f, accp0 = 0.f, accp1 = 0.f, accg = 0.f;
  const f32x4 zf = {0.f, 0.f, 0.f, 0.f};

  for (int it = 0; it < NT_FB; ++it) {
    const int cur = it & 1, nxt = (it + 1) & 1;
    const bool hasn1 = (it + 1 < NT_FB);
    const bool hasn2 = (it + 2 < NT_FB);
    const int e0n = (hasn1 ? (tile0 + it + 1) : tile0) * 64;
    const int e0n2 = (hasn2 ? (tile0 + it + 2) : tile0) * 64;

    float4 epre = *reinterpret_cast<const float4*>(E_b + (size_t)e0n * 16 + tid * 4);
    int idxpre = 0;
    if (tid < 128) idxpre = edges_b[(size_t)e0n2 * 2 + tid];
    const int node = idx_lds[nxt][gpos];
    bf16x8 p0v, p1v, p2v, p3v, p4v, p5v, p6v, p7v;
    GATHER8(node, p0v, p1v, p2v, p3v, p4v, p5v, p6v, p7v);

#pragma unroll
    for (int rt = 0; rt < 4; ++rt) {
      const short* arow = &A_lds[(rt * 16 + fc) * 296 + fg * 8];
      f32x4 a0 = zf, a1 = zf;
#pragma unroll
      for (int kt = 0; kt < 9; ++kt) {
        bf16x8 av = *reinterpret_cast<const bf16x8*>(arow + kt * 32);
        a0 = mfma16(av, B1[0][kt], a0);
        a1 = mfma16(av, B1[1][kt], a1);
      }
      bf16x8 av8 = *reinterpret_cast<const bf16x8*>(arow + 256);
      f32x4 q0 = mfma16(av8, PWf[0], zf);
      f32x4 q1 = mfma16(av8, PWf[1], zf);
#pragma unroll
      for (int r = 0; r < 4; ++r) {
        int row = rt * 16 + fg * 4 + r;
        float g = gate_lds[cur][row];
        accp0 += q0[r] * g;
        accp1 += q1[r] * g;
        h1_lds[row * 136 + ncol0 + fc] = (short)f2bf(fmaxf(a0[r] + eb1v[0], 0.f));
        h1_lds[row * 136 + ncol0 + 16 + fc] = (short)f2bf(fmaxf(a1[r] + eb1v[1], 0.f));
      }
    }
    __syncthreads();

    if (hasn1) {
      STORE8(p0v, p1v, p2v, p3v, p4v, p5v, p6v, p7v);
      ushort4 evb; evb.x = f2bf(epre.x); evb.y = f2bf(epre.y); evb.z = f2bf(epre.z); evb.w = f2bf(epre.w);
      *reinterpret_cast<ushort4*>(&A_lds[et * 296 + 256 + q * 4]) = evb;
      if (q == 0) gate_lds[nxt][et] = fminf(fmaxf(1.f + gs * epre.z, 0.f), 3.f);
      if (tid < 128) idx_lds[cur][tid] = idxpre;
    }

    if (w == 0) accg += gate_lds[cur][lane];
#pragma unroll
    for (int rt = 0; rt < 4; ++rt) {
      const short* hrow = &h1_lds[(rt * 16 + fc) * 136 + fg * 8];
      f32x4 a0 = zf, a1 = zf;
#pragma unroll
      for (int kt = 0; kt < 4; ++kt) {
        bf16x8 hv = *reinterpret_cast<const bf16x8*>(hrow + kt * 32);
        a0 = mfma16(hv, B2[0][kt], a0);
        a1 = mfma16(hv, B2[1][kt], a1);
      }
#pragma unroll
      for (int r = 0; r < 4; ++r) {
        int row = rt * 16 + fg * 4 + r;
        float g = gate_lds[cur][row];
        accm0 += fmaxf(a0[r] + eb2v[0], 0.f) * g;
        accm1 += fmaxf(a1[r] + eb2v[1], 0.f) * g;
      }
    }
    __syncthreads();
  }

  accm0 += __shfl_xor(accm0, 16); accm0 += __shfl_xor(accm0, 32);
  accm1 += __shfl_xor(accm1, 16); accm1 += __shfl_xor(accm1, 32);
  accp0 += __shfl_xor(accp0, 16); accp0 += __shfl_xor(accp0, 32);
  accp1 += __shfl_xor(accp1, 16); accp1 += __shfl_xor(accp1, 32);
  const int stripe = blockIdx.x & (STRIPES - 1);
  float* base = edge_acc + ((size_t)b * STRIPES + stripe) * 264;
  if (fg == 0) {
    atomicAdd(base + ncol0 + fc, accm0);
    atomicAdd(base + ncol0 + 16 + fc, accm1);
    atomicAdd(base + 128 + ncol0 + fc, accp0);
    atomicAdd(base + 128 + ncol0 + 16 + fc, accp1);
  }
  if (w == 0) {
#pragma unroll
    for (int off = 1; off < 64; off <<= 1) accg += __shfl_xor(accg, off);
    if (lane == 0) atomicAdd(base + 256, accg);
  }
#undef GATHER8
#undef STORE8
}

// ---------------- final combine + readout head (exact f32, both paths) ----------------

__global__ void final_kernel(const float* __restrict__ edge_acc, const float* __restrict__ node_acc,
                             const float* __restrict__ pb, const float* __restrict__ rW1,
                             const float* __restrict__ rb1, const float* __restrict__ rW2,
                             const float* __restrict__ rb2, float* __restrict__ out) {
  int b = blockIdx.x;
  int j = threadIdx.x;  // 0..127
  __shared__ float feat[256];
  __shared__ float h[64];
  const float* ea = edge_acc + (size_t)b * STRIPES * 264;
  const float* na = node_acc + (size_t)b * STRIPES * 128;
  float ms = 0.f, ps = 0.f, hs = 0.f, gsum = 0.f;
  for (int s = 0; s < STRIPES; ++s) {
    ms += ea[s * 264 + j];
    ps += ea[s * 264 + 128 + j];
    hs += na[s * 128 + j];
    gsum += ea[s * 264 + 256];
  }
  feat[j] = (hs + 2.f * ms) * (1.f / (float)NN);
  feat[128 + j] = (ps + gsum * pb[j]) / ((float)ME + 1e-6f);
  __syncthreads();
  if (j < 64) {
    float a = rb1[j];
    for (int i = 0; i < 256; ++i) a += feat[i] * rW1[i * 64 + j];
    h[j] = fmaxf(a, 0.f);
  }
  __syncthreads();
  if (j < 2) {
    float a = rb2[j];
    for (int i = 0; i < 64; ++i) a += h[i] * rW2[i * 2 + j];
    out[b * 2 + j] = a;
  }
}

// ---------------- host ----------------

extern "C" void kernel_launch(void* const* d_in, const int* in_sizes, int n_in,
                              void* d_out, int out_size, void* d_ws, size_t ws_size,
                              hipStream_t stream) {
  const float* X = (const float*)d_in[0];
  const float* E = (const float*)d_in[1];
  const int* edges = (const int*)d_in[2];
  const float* nW1 = (const float*)d_in[3];
  const float* nb1 = (const float*)d_in[4];
  const float* nW2 = (const float*)d_in[5];
  const float* nb2 = (const float*)d_in[6];
  const float* eW1 = (const float*)d_in[7];
  const float* eb1 = (const float*)d_in[8];
  const float* eW2 = (const float*)d_in[9];
  const float* eb2 = (const float*)d_in[10];
  const float* pW = (const float*)d_in[11];
  const float* pb = (const float*)d_in[12];
  const float* rW1 = (const float*)d_in[13];
  const float* rb1 = (const float*)d_in[14];
  const float* rW2 = (const float*)d_in[15];
  const float* rb2 = (const float*)d_in[16];
  const float* gscale = (const float*)d_in[17];
  float* out = (float*)d_out;

  char* ws = (char*)d_ws;
  size_t off = 0;
  auto alloc = [&](size_t sz) -> void* {
    void* p = ws + off;
    off = (off + sz + 255) & ~(size_t)255;
    return p;
  };
  size_t acc_floats = (size_t)NB * STRIPES * 264 + (size_t)NB * STRIPES * 128;

  // ---- new-path layout (fp16 Xs/Xd) ----
  short* es1T = (short*)alloc(128 * 128 * 2);
  short* ed1T = (short*)alloc(128 * 128 * 2);
  short* w1eT = (short*)alloc(128 * 32 * 2);
  short* ew2T = (short*)alloc(128 * 128 * 2);
  short* nw1T = (short*)alloc(128 * 128 * 2);
  short* nw2T = (short*)alloc(128 * 128 * 2);
  short* pwT  = (short*)alloc(128 * 32 * 2);
  float* acc  = (float*)alloc(acc_floats * 4);
  unsigned short* Xs = (unsigned short*)alloc((size_t)NB * NN * 128 * 2);
  unsigned short* Xd = (unsigned short*)alloc((size_t)NB * NN * 128 * 2);
  bool fit = off <= ws_size;

  if (fit) {
    float* edge_acc = acc;
    float* node_acc = acc + (size_t)NB * STRIPES * 264;
    prep_w2<<<dim3(128), dim3(256), 0, stream>>>(eW1, eW2, nW1, nW2, pW,
                                                 es1T, ed1T, w1eT, ew2T, nw1T, nw2T, pwT,
                                                 acc, (int)acc_floats);
    node_prep<<<dim3(313, 2), dim3(256), 0, stream>>>(X, nw1T, nw2T, es1T, ed1T,
                                                      nb1, nb2, Xs, Xd, node_acc);
    edge_kernel5<<<dim3(1000, 2), dim3(256), 0, stream>>>(Xs, Xd, E, edges, w1eT, pwT,
                                                          ew2T, eb1, eb2, gscale, edge_acc);
    final_kernel<<<dim3(NB), dim3(128), 0, stream>>>(edge_acc, node_acc, pb, rW1, rb1, rW2, rb2, out);
    return;
  }

  // ---- fallback: round-3 layout & kernels ----
  off = 0;
  short* ew1T_f = (short*)alloc(288 * 128 * 2);
  short* ew2T_f = (short*)alloc(128 * 128 * 2);
  short* nw1T_f = (short*)alloc(128 * 128 * 2);
  short* nw2T_f = (short*)alloc(128 * 128 * 2);
  short* pwT_f  = (short*)alloc(32 * 128 * 2);
  float* acc_f  = (float*)alloc(acc_floats * 4);
  float* edge_acc = acc_f;
  float* node_acc = acc_f + (size_t)NB * STRIPES * 264;
  size_t xbf_bytes = (size_t)NB * NN * 128 * 2;
  size_t off_before_xbf = off;
  short* Xbf = (short*)alloc(xbf_bytes);
  bool use_xbf = (off_before_xbf + xbf_bytes) <= ws_size;

  hipMemsetAsync(acc_f, 0, acc_floats * 4, stream);
  prep_w_fb<<<dim3(128), dim3(256), 0, stream>>>(eW1, eW2, nW1, nW2, pW,
                                                 ew1T_f, ew2T_f, nw1T_f, nw2T_f, pwT_f);
  if (use_xbf) {
    node_kernel_fb<true><<<dim3(313, 2), dim3(256), 0, stream>>>(X, Xbf, nw1T_f, nw2T_f, nb1, nb2, node_acc);
    edge_kernel_fb<true><<<dim3(625, 2), dim3(256), 0, stream>>>(
        Xbf, X, E, edges, ew1T_f, ew2T_f, pwT_f, eb1, eb2, gscale, edge_acc);
  } else {
    node_kernel_fb<false><<<dim3(313, 2), dim3(256), 0, stream>>>(X, Xbf, nw1T_f, nw2T_f, nb1, nb2, node_acc);
    edge_kernel_fb<false><<<dim3(625, 2), dim3(256), 0, stream>>>(
        Xbf, X, E, edges, ew1T_f, ew2T_f, pwT_f, eb1, eb2, gscale, edge_acc);
  }
  final_kernel<<<dim3(NB), dim3(128), 0, stream>>>(edge_acc, node_acc, pb, rW1, rb1, rW2, rb2, out);
}